// Round 13
// baseline (459.932 us; speedup 1.0000x reference)
//
#include <hip/hip_runtime.h>
#include <cstdint>

// Problem constants (static per reference)
#define T_TOK 16384     // B*S
#define HD    1024      // H
#define NE    8         // experts
#define CAP   2560      // ceil(1.25*T/E)
#define NCHUNK (T_TOK / 64)   // 256

typedef __attribute__((ext_vector_type(4))) float f32x4;
typedef __attribute__((ext_vector_type(8))) short bf16x8;   // 8 bf16 = 4 VGPRs

__device__ __forceinline__ unsigned short f2bf(float f) {
    union { float f; unsigned u; } x{f};
    unsigned r = x.u + 0x7FFF + ((x.u >> 16) & 1);   // RNE
    return (unsigned short)(r >> 16);
}

__device__ __forceinline__ void gload_lds16(const unsigned short* g, unsigned short* l) {
    __builtin_amdgcn_global_load_lds(
        (const __attribute__((address_space(1))) void*)g,
        (__attribute__((address_space(3))) void*)l, 16, 0, 0);
}

// ---------------------------------------------------------------------------
// bf16 MFMA GEMM: C[M,N] = op(A[M,K] @ Bt[N,K]^T [+ bias[N]])
// R10/R12 structure (measured local optimum): 256x128 tile, BK=64, 8 waves,
// single-buffer 2-barrier loop; XCD bijective swizzle; XOR chunk-swizzle
// (0 bank conflicts); empty-tile early-exit for expert GEMMs.
// Epilogues:
//   RELU:     v = max(acc+bias, 0)
//   ROWSCALE: v = rs[m]*(acc+bias) + post[n]          (f32 or bf16 store)
//   SCATTER:  C[tab[m]] += rs[tab[m]]*(acc+bias)      (f32 RMW, skip tab<0)
//   OUTBF16:  bf16 store else f32
// bias may be nullptr (skipped).
// ---------------------------------------------------------------------------
template<bool GATHER, bool RELU, bool ROWSCALE, bool SCATTER, bool OUTBF16>
__global__ __launch_bounds__(512)
void gemm_bf16_k(const unsigned short* __restrict__ A,
                 const unsigned short* __restrict__ Bt,
                 const float* __restrict__ bias,
                 void* __restrict__ Cv,
                 int M, int N, int K,
                 const int* __restrict__ idxTab,
                 const float* __restrict__ rs,
                 const float* __restrict__ post,
                 long aB, long bB, long biasB, long tabB, long cB)
{
    // ---- XCD-aware remap: XCD c gets contiguous logical chunk ----
    const int nx = gridDim.x, ny = gridDim.y;
    long nwg = (long)nx * ny * gridDim.z;
    long flat = blockIdx.x + (long)nx * (blockIdx.y + (long)ny * blockIdx.z);
    long cpx = nwg >> 3;                       // nwg % 8 == 0 by construction
    long swz = (flat & 7) * cpx + (flat >> 3);
    const int bx = (int)(swz % nx);
    const int by = (int)((swz / nx) % ny);
    const int bz = (int)(swz / ((long)nx * ny));

    A  += (long)bz * aB;
    Bt += (long)bz * bB;
    const float* bptr = bias ? bias + (long)bz * biasB : nullptr;
    const int* tab = idxTab ? idxTab + (long)bz * tabB : nullptr;
    float*          Cf = (float*)Cv + (long)bz * cB;
    unsigned short* Cb = (unsigned short*)Cv + (long)bz * cB;

    const int m0 = by * 256, n0 = bx * 128;

    // empty-tile early-exit (uniform across block; before any barrier)
    if ((GATHER || SCATTER) && tab[m0] < 0) return;

    __shared__ unsigned short As[256][64];   // 32 KB, row = m
    __shared__ unsigned short Bs[128][64];   // 16 KB, row = n  (48 KB total)

    const int tid  = threadIdx.x;
    const int wv   = tid >> 6;               // 0..7
    const int lane = tid & 63;

    // staging: issue = 8 rows x 128 B = 1024 B = 64 lanes x 16 B.
    const int srow = lane >> 3;
    const int schk = lane & 7;

    const unsigned short* aSrc[4];           // wave stages A rows wv*32..+31
    const unsigned short* bSrc[2];           // wave stages B rows wv*16..+15
    #pragma unroll
    for (int i = 0; i < 4; ++i) {
        int lrow = wv * 32 + i * 8 + srow;          // 0..255
        int scol = ((schk ^ (lrow & 7)) * 8);       // swizzled col (elems)
        long sr;
        if (GATHER) { int tr = tab[m0 + lrow]; sr = tr < 0 ? 0 : tr; }
        else        sr = m0 + lrow;
        aSrc[i] = A + sr * (long)K + scol;
    }
    #pragma unroll
    for (int i = 0; i < 2; ++i) {
        int lrow = wv * 16 + i * 8 + srow;          // 0..127
        int scol = ((schk ^ (lrow & 7)) * 8);
        bSrc[i] = Bt + (long)(n0 + lrow) * K + scol;
    }

    f32x4 acc[4][4] = {};
    const int wm = wv >> 1, wn = wv & 1;     // 4 x 2 wave grid
    const int fr = lane & 15, kg = lane >> 4;

    for (int k0 = 0; k0 < K; k0 += 64) {
        __syncthreads();                     // prev tile fully consumed
        #pragma unroll
        for (int i = 0; i < 4; ++i)
            gload_lds16(aSrc[i] + k0, &As[wv * 32 + i * 8][0]);
        #pragma unroll
        for (int i = 0; i < 2; ++i)
            gload_lds16(bSrc[i] + k0, &Bs[wv * 16 + i * 8][0]);
        __syncthreads();                     // vmcnt(0) drained here

        #pragma unroll
        for (int kk = 0; kk < 2; ++kk) {     // two K=32 halves of BK=64
            bf16x8 af[4], bfr[4];
            #pragma unroll
            for (int i2 = 0; i2 < 4; ++i2) {
                int R = wm * 64 + i2 * 16 + fr;
                af[i2] = *(const bf16x8*)&As[R][((kk * 4 + kg) ^ (R & 7)) * 8];
            }
            #pragma unroll
            for (int j2 = 0; j2 < 4; ++j2) {
                int R = wn * 64 + j2 * 16 + fr;
                bfr[j2] = *(const bf16x8*)&Bs[R][((kk * 4 + kg) ^ (R & 7)) * 8];
            }
            #pragma unroll
            for (int i2 = 0; i2 < 4; ++i2)
                #pragma unroll
                for (int j2 = 0; j2 < 4; ++j2)
                    acc[i2][j2] = __builtin_amdgcn_mfma_f32_16x16x32_bf16(
                        af[i2], bfr[j2], acc[i2][j2], 0, 0, 0);
        }
    }

    // epilogue: C/D layout col = lane&15, row = (lane>>4)*4 + r
    const int colL = lane & 15, rgrp = (lane >> 4) * 4;
    #pragma unroll
    for (int i2 = 0; i2 < 4; ++i2) {
        #pragma unroll
        for (int r = 0; r < 4; ++r) {
            int gm = m0 + wm * 64 + i2 * 16 + rgrp + r;
            int token = gm; float sc = 1.0f;
            if (SCATTER) {
                token = tab[gm];
                if (token < 0) continue;
                sc = rs[token];
            } else if (ROWSCALE) {
                sc = rs[gm];
            }
            #pragma unroll
            for (int j2 = 0; j2 < 4; ++j2) {
                int gn = n0 + wn * 64 + j2 * 16 + colL;
                float v = acc[i2][j2][r] + (bptr ? bptr[gn] : 0.0f);
                if (RELU) v = fmaxf(v, 0.0f);
                if (SCATTER) {
                    Cf[(long)token * N + gn] += v * sc;     // unique writer
                } else {
                    if (ROWSCALE) {
                        v = v * sc + (post ? post[gn] : 0.0f);
                    }
                    if (OUTBF16) Cb[(long)gm * N + gn] = f2bf(v);
                    else         Cf[(long)gm * N + gn] = v;
                }
            }
        }
    }
}

// ---------------------------------------------------------------------------
// f32 -> bf16 cast (vectorized, grid-stride)
// ---------------------------------------------------------------------------
__global__ __launch_bounds__(256)
void cast_bf16_k(const float* __restrict__ in, unsigned short* __restrict__ out,
                 long n4)
{
    long i = (long)blockIdx.x * 256 + threadIdx.x;
    long stride = (long)gridDim.x * 256;
    for (; i < n4; i += stride) {
        float4 v = ((const float4*)in)[i];
        ushort4 o;
        o.x = f2bf(v.x); o.y = f2bf(v.y); o.z = f2bf(v.z); o.w = f2bf(v.w);
        ((ushort4*)out)[i] = o;
    }
}

// ---------------------------------------------------------------------------
// Transpose + cast: W[K][N] f32 -> Wt[N][K] bf16, 64x64 LDS tiles. z batched.
// ---------------------------------------------------------------------------
__global__ __launch_bounds__(256)
void transpose_cast_k(const float* __restrict__ W, unsigned short* __restrict__ Wt,
                      int K, int N, long wB, long wtB)
{
    const int z = blockIdx.z;
    W  += (long)z * wB;
    Wt += (long)z * wtB;
    __shared__ float tile[64][65];
    const int k0 = blockIdx.x * 64, n0 = blockIdx.y * 64;
    const int c = threadIdx.x & 63, r4 = threadIdx.x >> 6;
    #pragma unroll 4
    for (int it = 0; it < 16; ++it) {
        int row = it * 4 + r4;
        tile[row][c] = W[(long)(k0 + row) * N + n0 + c];
    }
    __syncthreads();
    #pragma unroll 4
    for (int it = 0; it < 16; ++it) {
        int nrow = it * 4 + r4;
        Wt[(long)(n0 + nrow) * K + k0 + c] = f2bf(tile[c][nrow]);
    }
}

// ---------------------------------------------------------------------------
// Fused-bias helpers: out[z][n] = sum_k v[z*vB+k] * W[z*wB + k*HD + n] (+badd)
// init writes the badd (or 0) base; acc atomically adds K-chunk partials.
// ---------------------------------------------------------------------------
__global__ void vecmat_init_k(const float* __restrict__ badd, long bB,
                              float* __restrict__ out, long oB)
{
    const int z = blockIdx.y;
    const int n = blockIdx.x * 256 + threadIdx.x;
    out[z * oB + n] = badd ? badd[z * bB + n] : 0.0f;
}

__global__ void vecmat_acc_k(const float* __restrict__ v, long vB,
                             const float* __restrict__ W, long wB,
                             float* __restrict__ out, long oB)
{
    const int z = blockIdx.z;
    const int n = blockIdx.x * 256 + threadIdx.x;
    const int kc = blockIdx.y;             // K chunk of 128
    const float* vp = v + z * vB;
    const float* Wp = W + z * wB;
    float acc = 0.f;
    #pragma unroll 8
    for (int k = kc * 128; k < kc * 128 + 128; ++k)
        acc = fmaf(vp[k], Wp[(long)k * HD + n], acc);
    atomicAdd(out + z * oB + n, acc);
}

// ---------------------------------------------------------------------------
// Wsmall: Wg'[H][8] = W_in @ W_gate, Wc'[H][2] = W_in @ W_coef  (f32)
// ---------------------------------------------------------------------------
__global__ __launch_bounds__(256)
void wsmall_k(const float* __restrict__ W_in, const float* __restrict__ W_gate,
              const float* __restrict__ W_coef,
              float* __restrict__ wgp, float* __restrict__ wcp)
{
    const int r = blockIdx.x * 4 + (threadIdx.x >> 6);
    const int lane = threadIdx.x & 63;
    float s[10] = {};
    for (int k = lane; k < HD; k += 64) {
        float a = W_in[(long)r * HD + k];
        const float4* g = (const float4*)(W_gate + (long)k * 8);
        float4 g0 = g[0], g1 = g[1];
        s[0] += a * g0.x; s[1] += a * g0.y; s[2] += a * g0.z; s[3] += a * g0.w;
        s[4] += a * g1.x; s[5] += a * g1.y; s[6] += a * g1.z; s[7] += a * g1.w;
        float2 cv = *(const float2*)(W_coef + (long)k * 2);
        s[8] += a * cv.x; s[9] += a * cv.y;
    }
    #pragma unroll
    for (int off = 32; off > 0; off >>= 1)
        #pragma unroll
        for (int e = 0; e < 10; ++e) s[e] += __shfl_xor(s[e], off);
    if (lane == 0) {
        #pragma unroll
        for (int e = 0; e < 8; ++e) wgp[(long)r * 8 + e] = s[e];
        wcp[(long)r * 2 + 0] = s[8];
        wcp[(long)r * 2 + 1] = s[9];
    }
}

// bg[8] = b_in @ W_gate ; bc[2] = b_in @ W_coef + b_coef
__global__ void gbias_k(const float* __restrict__ b_in, const float* __restrict__ W_gate,
                        const float* __restrict__ W_coef, const float* __restrict__ b_coef,
                        float* __restrict__ bg, float* __restrict__ bc)
{
    const int lane = threadIdx.x;  // 64
    float s[10] = {};
    for (int k = lane; k < HD; k += 64) {
        float a = b_in[k];
        const float4* g = (const float4*)(W_gate + (long)k * 8);
        float4 g0 = g[0], g1 = g[1];
        s[0] += a * g0.x; s[1] += a * g0.y; s[2] += a * g0.z; s[3] += a * g0.w;
        s[4] += a * g1.x; s[5] += a * g1.y; s[6] += a * g1.z; s[7] += a * g1.w;
        float2 cv = *(const float2*)(W_coef + (long)k * 2);
        s[8] += a * cv.x; s[9] += a * cv.y;
    }
    #pragma unroll
    for (int off = 32; off > 0; off >>= 1)
        #pragma unroll
        for (int e = 0; e < 10; ++e) s[e] += __shfl_xor(s[e], off);
    if (lane == 0) {
        #pragma unroll
        for (int e = 0; e < 8; ++e) bg[e] = s[e];
        bc[0] = s[8] + b_coef[0];
        bc[1] = s[9] + b_coef[1];
    }
}

// ---------------------------------------------------------------------------
// Gating from x with fused weights (one wave per token) + fused x->bf16 cast.
// ---------------------------------------------------------------------------
__global__ __launch_bounds__(256)
void gating_k(const float* __restrict__ x,
              const float* __restrict__ Wg,   // [H,8] fused
              const float* __restrict__ Wc,   // [H,2] fused
              const float* __restrict__ bg,   // [8]
              const float* __restrict__ bc,   // [2]
              unsigned short* __restrict__ xb,
              int* __restrict__ eidx,
              float* __restrict__ gval,
              float* __restrict__ coef0,
              float* __restrict__ coef1)
{
    const int tok = (blockIdx.x * 256 + threadIdx.x) >> 6;
    const int lane = threadIdx.x & 63;
    const float* row = x + (long)tok * HD;
    unsigned short* orow = xb + (long)tok * HD;

    float acc[8] = {};
    float c0 = 0.f, c1 = 0.f;
    for (int i = 0; i < HD / 64; ++i) {
        int k = i * 64 + lane;
        float tv = row[k];
        orow[k] = f2bf(tv);                      // fused x -> bf16 (coalesced)
        const float4* wg = (const float4*)(Wg + (long)k * 8);
        float4 w0 = wg[0], w1 = wg[1];
        acc[0] = fmaf(tv, w0.x, acc[0]); acc[1] = fmaf(tv, w0.y, acc[1]);
        acc[2] = fmaf(tv, w0.z, acc[2]); acc[3] = fmaf(tv, w0.w, acc[3]);
        acc[4] = fmaf(tv, w1.x, acc[4]); acc[5] = fmaf(tv, w1.y, acc[5]);
        acc[6] = fmaf(tv, w1.z, acc[6]); acc[7] = fmaf(tv, w1.w, acc[7]);
        float2 wcv = *(const float2*)(Wc + (long)k * 2);
        c0 = fmaf(tv, wcv.x, c0);
        c1 = fmaf(tv, wcv.y, c1);
    }
    #pragma unroll
    for (int off = 32; off > 0; off >>= 1) {
        #pragma unroll
        for (int e = 0; e < 8; ++e) acc[e] += __shfl_xor(acc[e], off);
        c0 += __shfl_xor(c0, off);
        c1 += __shfl_xor(c1, off);
    }
    if (lane == 0) {
        #pragma unroll
        for (int e = 0; e < 8; ++e) acc[e] += bg[e];
        float m = acc[0]; int best = 0;
        #pragma unroll
        for (int e = 1; e < 8; ++e) if (acc[e] > m) { m = acc[e]; best = e; }
        float s = 0.f;
        #pragma unroll
        for (int e = 0; e < 8; ++e) s += expf(acc[e] - m);
        eidx[tok] = best;
        gval[tok] = 1.0f / s;
        float l0 = c0 + bc[0], l1 = c1 + bc[1];
        float mm = fmaxf(l0, l1);
        float e0 = expf(l0 - mm), e1 = expf(l1 - mm);
        float inv = 1.0f / (e0 + e1);
        coef0[tok] = e0 * inv;
        coef1[tok] = e1 * inv;
    }
}

// ---------------------------------------------------------------------------
// Parallel capacity scan, 3 phases (integer-exact, verified round 5).
// ---------------------------------------------------------------------------
__global__ void scan_hist_k(const int* __restrict__ eidx,
                            int* __restrict__ counts,
                            int* __restrict__ idxTab)
{
    const int b = blockIdx.x;          // chunk id, 0..255
    const int lane = threadIdx.x;      // 64
    for (int j = b * 64 + lane; j < NE * CAP; j += NCHUNK * 64)
        idxTab[j] = -1;
    int e = eidx[b * 64 + lane];
    #pragma unroll
    for (int ex = 0; ex < NE; ++ex) {
        unsigned long long msk = __ballot(e == ex);
        if (lane == ex) counts[b * NE + ex] = (int)__popcll(msk);
    }
}

__global__ void scan_offsets_k(const int* __restrict__ counts,
                               int* __restrict__ offsets)
{
    const int e = threadIdx.x;         // 64 threads, 8 active
    if (e < NE) {
        int run = 0;
        for (int b = 0; b < NCHUNK; ++b) {
            offsets[b * NE + e] = run;
            run += counts[b * NE + e];
        }
    }
}

__global__ void scan_fill_k(const int* __restrict__ eidx,
                            const float* __restrict__ gval,
                            const float* __restrict__ coef0,
                            const int* __restrict__ offsets,
                            int* __restrict__ idxTab,
                            float* __restrict__ smoe)
{
    const int b = blockIdx.x;
    const int lane = threadIdx.x;
    const int tok = b * 64 + lane;
    int e = eidx[tok];
    unsigned long long below = (lane == 0) ? 0ull : ((~0ull) >> (64 - lane));
    int myrank = 0;
    #pragma unroll
    for (int ex = 0; ex < NE; ++ex) {
        unsigned long long msk = __ballot(e == ex);
        if (e == ex) myrank = (int)__popcll(msk & below) + offsets[b * NE + ex];
    }
    if (myrank < CAP) {
        idxTab[e * CAP + myrank] = tok;
        smoe[tok] = gval[tok] * coef0[tok];
    } else {
        smoe[tok] = 0.0f;
    }
}

// ---------------------------------------------------------------------------
// Workspace plan (lifetime-aliased; ~109 MB):
//   [0,40Mi):   pre-fusion weights W1T(16)+Wr1T(2)+Winp(2)+Wr2p(2)+W2p(16)+
//               WoutT(2) — dead after wfuse; h(40) overlays for FC1..k'
//   [40,76Mi):  WF1T(16)+WFr1T(2)+WFr2T(2)+WF2T(16)  (fused, live to k')
//   [76,108Mi): res1 (32)
//   [108Mi..):  small (biases, routing arrays)
//   xb: d_out[0,32Mi) (dies after i);  out: d_out f32 (written j', RMW k')
// ---------------------------------------------------------------------------
extern "C" void kernel_launch(void* const* d_in, const int* in_sizes, int n_in,
                              void* d_out, int out_size, void* d_ws, size_t ws_size,
                              hipStream_t stream)
{
    const float* x      = (const float*)d_in[0];
    const float* W_in   = (const float*)d_in[1];
    const float* b_in   = (const float*)d_in[2];
    const float* W_gate = (const float*)d_in[3];
    const float* W1     = (const float*)d_in[4];
    const float* b1     = (const float*)d_in[5];
    const float* W2     = (const float*)d_in[6];
    const float* b2     = (const float*)d_in[7];
    const float* Wr1    = (const float*)d_in[8];
    const float* br1    = (const float*)d_in[9];
    const float* Wr2    = (const float*)d_in[10];
    const float* br2    = (const float*)d_in[11];
    const float* W_coef = (const float*)d_in[12];
    const float* b_coef = (const float*)d_in[13];
    const float* W_out  = (const float*)d_in[14];
    const float* b_out  = (const float*)d_in[15];
    float* out = (float*)d_out;

    const size_t MiB = 1024 * 1024;
    char* ws = (char*)d_ws;
    // pre-fusion (dead after wfuse); h overlays [0,40Mi)
    unsigned short* W1T   = (unsigned short*)(ws + 0);         // 16 MiB (z=8)
    unsigned short* Wr1T  = (unsigned short*)(ws + 16 * MiB);  // 2 MiB (A-batch after W1T)
    unsigned short* Winp  = (unsigned short*)(ws + 18 * MiB);  // 2 MiB plain cast
    unsigned short* Wr2p  = (unsigned short*)(ws + 20 * MiB);  // 2 MiB (Bt-batch head)
    unsigned short* W2p   = (unsigned short*)(ws + 22 * MiB);  // 16 MiB (Bt-batch tail)
    unsigned short* WoutT = (unsigned short*)(ws + 38 * MiB);  // 2 MiB
    unsigned short* h     = (unsigned short*)(ws + 0);         // 40 MiB overlay
    // fused weights (live until k')
    unsigned short* WF1T  = (unsigned short*)(ws + 40 * MiB);  // 16 MiB
    unsigned short* WFr1T = (unsigned short*)(ws + 56 * MiB);  // 2 MiB (C-batch after WF1T)
    unsigned short* WFr2T = (unsigned short*)(ws + 58 * MiB);  // 2 MiB (C-batch head)
    unsigned short* WF2T  = (unsigned short*)(ws + 60 * MiB);  // 16 MiB (C-batch tail)
    unsigned short* res1  = (unsigned short*)(ws + 76 * MiB);  // 32 MiB
    char* sm = ws + 108 * MiB;
    float* wgp  = (float*)(sm);            sm += HD * 8 * 4;
    float* wcp  = (float*)(sm);            sm += HD * 2 * 4;
    float* bg   = (float*)(sm);            sm += 64;
    float* bc   = (float*)(sm);            sm += 64;
    float* bf1  = (float*)(sm);            sm += NE * HD * 4;   // b_in@W1[e]+b1[e]
    float* bfr1 = (float*)(sm);            sm += HD * 4;        // b_in@Wr1+br1
    float* c2   = (float*)(sm);            sm += HD * 4;        // br2@W_out
    float* c3   = (float*)(sm);            sm += NE * HD * 4;   // b2[e]@W_out
    int*   eidx = (int*)(sm);              sm += T_TOK * 4;
    float* gval = (float*)(sm);            sm += T_TOK * 4;
    float* cf0  = (float*)(sm);            sm += T_TOK * 4;
    float* cf1  = (float*)(sm);            sm += T_TOK * 4;
    float* smoe = (float*)(sm);            sm += T_TOK * 4;
    int* idxTab = (int*)(sm);              sm += NE * CAP * 4;
    int* counts = (int*)(sm);              sm += NCHUNK * NE * 4;
    int* offs   = (int*)(sm);              sm += NCHUNK * NE * 4;
    unsigned short* xb = (unsigned short*)d_out;   // 32 MiB, dies after step i
    (void)ws_size; (void)in_sizes; (void)n_in; (void)out_size;

    const long HD2 = (long)HD * HD;
    dim3 blk(256);
    dim3 blkG(512);
    dim3 gT(16, 16, 1);
    dim3 gT8(16, 16, 8);
    dim3 gBig(HD / 128, T_TOK / 256, 1);   // 8 x 64 = 512 blocks (%8==0)
    dim3 gExp(HD / 128, CAP / 256, NE);    // 8 x 10 x 8 = 640 blocks (%8==0)
    dim3 gFuse(HD / 128, HD / 256, 9);     // 8 x 4 x 9 = 288 blocks (%8==0)

    // 1. weight transposes (bf16 [N][K]) — only what feeds wfuse A-operands
    transpose_cast_k<<<gT8, blk, 0, stream>>>(W1, W1T, HD, HD, HD2, HD2);
    transpose_cast_k<<<gT,  blk, 0, stream>>>(Wr1,   Wr1T,  HD, HD, 0, 0);
    transpose_cast_k<<<gT,  blk, 0, stream>>>(W_out, WoutT, HD, HD, 0, 0);
    // 2. plain casts — wfuse Bt-operands (row-major [K][N] as [m][k] rows)
    cast_bf16_k<<<512,  blk, 0, stream>>>(W_in, Winp, HD2 / 4);
    cast_bf16_k<<<512,  blk, 0, stream>>>(Wr2,  Wr2p, HD2 / 4);
    cast_bf16_k<<<2048, blk, 0, stream>>>(W2,   W2p,  (long)NE * HD2 / 4);
    // 3. fused gating weights + biases (f32 routing path)
    wsmall_k<<<HD / 4, blk, 0, stream>>>(W_in, W_gate, W_coef, wgp, wcp);
    gbias_k<<<1, 64, 0, stream>>>(b_in, W_gate, W_coef, b_coef, bg, bc);
    // 4. fused biases: bf1, bfr1, c2, c3
    { dim3 gi(HD / 256, NE), ga(HD / 256, NE, NE);  // note: ga.y is K/128=8
      vecmat_init_k<<<dim3(HD/256, NE), blk, 0, stream>>>(b1, HD, bf1, HD);
      vecmat_acc_k <<<dim3(HD/256, 8, NE), blk, 0, stream>>>(b_in, 0, W1, HD2, bf1, HD);
      vecmat_init_k<<<dim3(HD/256, 1), blk, 0, stream>>>(br1, 0, bfr1, 0);
      vecmat_acc_k <<<dim3(HD/256, 8, 1), blk, 0, stream>>>(b_in, 0, Wr1, 0, bfr1, 0);
      vecmat_init_k<<<dim3(HD/256, 1), blk, 0, stream>>>(nullptr, 0, c2, 0);
      vecmat_acc_k <<<dim3(HD/256, 8, 1), blk, 0, stream>>>(br2, 0, W_out, 0, c2, 0);
      vecmat_init_k<<<dim3(HD/256, NE), blk, 0, stream>>>(nullptr, 0, c3, HD);
      vecmat_acc_k <<<dim3(HD/256, 8, NE), blk, 0, stream>>>(b2, HD, W_out, 0, c3, HD);
    }
    // 5. gating from x (f32 routing) + fused x->bf16 cast into d_out
    gating_k<<<T_TOK / 4, blk, 0, stream>>>(x, wgp, wcp, bg, bc, xb,
                                            eidx, gval, cf0, cf1);
    // 6. parallel capacity scan
    scan_hist_k<<<NCHUNK, 64, 0, stream>>>(eidx, counts, idxTab);
    scan_offsets_k<<<1, 64, 0, stream>>>(counts, offs);
    scan_fill_k<<<NCHUNK, 64, 0, stream>>>(eidx, gval, cf0, offs, idxTab, smoe);
    // 7. weight fusion A: [WF1T(8), WFr1T] = [W1T(8), Wr1T] x Winp  (z=9)
    gemm_bf16_k<false, false, false, false, true><<<gFuse, blkG, 0, stream>>>(
        W1T, Winp, nullptr, WF1T, HD, HD, HD, nullptr, nullptr, nullptr,
        HD2, 0, 0, 0, HD2);
    // 8. weight fusion B: [WFr2T, WF2T(8)] = WoutT x [Wr2p, W2p(8)]  (z=9)
    gemm_bf16_k<false, false, false, false, true><<<gFuse, blkG, 0, stream>>>(
        WoutT, Wr2p, nullptr, WFr2T, HD, HD, HD, nullptr, nullptr, nullptr,
        0, HD2, 0, 0, HD2);
    // 9. h[e] = relu(gather(xb) @ WF1[e] + bf1[e])   bf16, empty-tile exit
    //    (h overlays the now-dead pre-fusion weight region)
    gemm_bf16_k<true, true, false, false, true><<<gExp, blkG, 0, stream>>>(
        xb, WF1T, bf1, h, CAP, HD, HD, idxTab, nullptr, nullptr,
        0, HD2, HD, CAP, (long)CAP * HD);
    // 10. res1 = relu(xb @ WFr1 + bfr1)   bf16
    gemm_bf16_k<false, true, false, false, true><<<gBig, blkG, 0, stream>>>(
        xb, WFr1T, bfr1, res1, T_TOK, HD, HD, nullptr, nullptr, nullptr,
        0, 0, 0, 0, 0);
    // 11. j': out = cf1[m]*(res1 @ WFr2 + c2) + b_out   f32 (kills xb)
    gemm_bf16_k<false, false, true, false, false><<<gBig, blkG, 0, stream>>>(
        res1, WFr2T, c2, out, T_TOK, HD, HD, nullptr, cf1, b_out,
        0, 0, 0, 0, 0);
    // 12. k': out[tok] += smoe[tok]*(h[e] @ WF2[e] + c3[e])  f32 RMW,
    //     empty-tile exit; dropped tokens need nothing (smoe contribution=0)
    gemm_bf16_k<false, false, false, true, false><<<gExp, blkG, 0, stream>>>(
        h, WF2T, c3, out, CAP, HD, HD, idxTab, smoe, nullptr,
        (long)CAP * HD, HD2, HD, CAP, 0);
}

// Round 14
// 459.511 us; speedup vs baseline: 1.0009x; 1.0009x over previous
//
#include <hip/hip_runtime.h>
#include <cstdint>

// Problem constants (static per reference)
#define T_TOK 16384     // B*S
#define HD    1024      // H
#define NE    8         // experts
#define CAP   2560      // ceil(1.25*T/E)
#define NCHUNK (T_TOK / 64)   // 256

typedef __attribute__((ext_vector_type(4))) float f32x4;
typedef __attribute__((ext_vector_type(8))) short bf16x8;   // 8 bf16 = 4 VGPRs

__device__ __forceinline__ unsigned short f2bf(float f) {
    union { float f; unsigned u; } x{f};
    unsigned r = x.u + 0x7FFF + ((x.u >> 16) & 1);   // RNE
    return (unsigned short)(r >> 16);
}

__device__ __forceinline__ void gload_lds16(const unsigned short* g, unsigned short* l) {
    __builtin_amdgcn_global_load_lds(
        (const __attribute__((address_space(1))) void*)g,
        (__attribute__((address_space(3))) void*)l, 16, 0, 0);
}

// ---------------------------------------------------------------------------
// bf16 MFMA GEMM: C[M,N] = op(A[M,K] @ Bt[N,K]^T [+ bias[N]])
// R12 structure (measured local optimum): 256x128 tile, BK=64, 8 waves,
// single-buffer 2-barrier loop; XCD bijective swizzle; XOR chunk-swizzle
// (0 bank conflicts); empty-tile early-exit for expert GEMMs.
// Epilogues:
//   RELU:            v = max(acc+bias, 0)
//   ROWSCALE:        v = rs[m]*(acc+bias)
//   SCATTER:         tok=tab[m]; skip<0; OUTBF16: Cb=f2bf(addsrc+v*rs[tok])
//                    else Cf += v*rs[tok]
//   OUTBF16:         bf16 store else f32
// bias may be nullptr.
// ---------------------------------------------------------------------------
template<bool GATHER, bool RELU, bool ROWSCALE, bool SCATTER, bool OUTBF16>
__global__ __launch_bounds__(512)
void gemm_bf16_k(const unsigned short* __restrict__ A,
                 const unsigned short* __restrict__ Bt,
                 const float* __restrict__ bias,
                 void* __restrict__ Cv,
                 int M, int N, int K,
                 const int* __restrict__ idxTab,
                 const float* __restrict__ rs,
                 const float* __restrict__ addsrc,
                 long aB, long bB, long biasB, long tabB, long cB)
{
    // ---- XCD-aware remap: XCD c gets contiguous logical chunk ----
    const int nx = gridDim.x, ny = gridDim.y;
    long nwg = (long)nx * ny * gridDim.z;
    long flat = blockIdx.x + (long)nx * (blockIdx.y + (long)ny * blockIdx.z);
    long cpx = nwg >> 3;                       // nwg % 8 == 0 by construction
    long swz = (flat & 7) * cpx + (flat >> 3);
    const int bx = (int)(swz % nx);
    const int by = (int)((swz / nx) % ny);
    const int bz = (int)(swz / ((long)nx * ny));

    A  += (long)bz * aB;
    Bt += (long)bz * bB;
    const float* bptr = bias ? bias + (long)bz * biasB : nullptr;
    const int* tab = idxTab ? idxTab + (long)bz * tabB : nullptr;
    float*          Cf = (float*)Cv + (long)bz * cB;
    unsigned short* Cb = (unsigned short*)Cv + (long)bz * cB;

    const int m0 = by * 256, n0 = bx * 128;

    // empty-tile early-exit (uniform across block; before any barrier)
    if ((GATHER || SCATTER) && tab[m0] < 0) return;

    __shared__ unsigned short As[256][64];   // 32 KB, row = m
    __shared__ unsigned short Bs[128][64];   // 16 KB, row = n  (48 KB total)

    const int tid  = threadIdx.x;
    const int wv   = tid >> 6;               // 0..7
    const int lane = tid & 63;

    // staging: issue = 8 rows x 128 B = 1024 B = 64 lanes x 16 B.
    const int srow = lane >> 3;
    const int schk = lane & 7;

    const unsigned short* aSrc[4];           // wave stages A rows wv*32..+31
    const unsigned short* bSrc[2];           // wave stages B rows wv*16..+15
    #pragma unroll
    for (int i = 0; i < 4; ++i) {
        int lrow = wv * 32 + i * 8 + srow;          // 0..255
        int scol = ((schk ^ (lrow & 7)) * 8);       // swizzled col (elems)
        long sr;
        if (GATHER) { int tr = tab[m0 + lrow]; sr = tr < 0 ? 0 : tr; }
        else        sr = m0 + lrow;
        aSrc[i] = A + sr * (long)K + scol;
    }
    #pragma unroll
    for (int i = 0; i < 2; ++i) {
        int lrow = wv * 16 + i * 8 + srow;          // 0..127
        int scol = ((schk ^ (lrow & 7)) * 8);
        bSrc[i] = Bt + (long)(n0 + lrow) * K + scol;
    }

    f32x4 acc[4][4] = {};
    const int wm = wv >> 1, wn = wv & 1;     // 4 x 2 wave grid
    const int fr = lane & 15, kg = lane >> 4;

    for (int k0 = 0; k0 < K; k0 += 64) {
        __syncthreads();                     // prev tile fully consumed
        #pragma unroll
        for (int i = 0; i < 4; ++i)
            gload_lds16(aSrc[i] + k0, &As[wv * 32 + i * 8][0]);
        #pragma unroll
        for (int i = 0; i < 2; ++i)
            gload_lds16(bSrc[i] + k0, &Bs[wv * 16 + i * 8][0]);
        __syncthreads();                     // vmcnt(0) drained here

        #pragma unroll
        for (int kk = 0; kk < 2; ++kk) {     // two K=32 halves of BK=64
            bf16x8 af[4], bfr[4];
            #pragma unroll
            for (int i2 = 0; i2 < 4; ++i2) {
                int R = wm * 64 + i2 * 16 + fr;
                af[i2] = *(const bf16x8*)&As[R][((kk * 4 + kg) ^ (R & 7)) * 8];
            }
            #pragma unroll
            for (int j2 = 0; j2 < 4; ++j2) {
                int R = wn * 64 + j2 * 16 + fr;
                bfr[j2] = *(const bf16x8*)&Bs[R][((kk * 4 + kg) ^ (R & 7)) * 8];
            }
            #pragma unroll
            for (int i2 = 0; i2 < 4; ++i2)
                #pragma unroll
                for (int j2 = 0; j2 < 4; ++j2)
                    acc[i2][j2] = __builtin_amdgcn_mfma_f32_16x16x32_bf16(
                        af[i2], bfr[j2], acc[i2][j2], 0, 0, 0);
        }
    }

    // epilogue: C/D layout col = lane&15, row = (lane>>4)*4 + r
    const int colL = lane & 15, rgrp = (lane >> 4) * 4;
    #pragma unroll
    for (int i2 = 0; i2 < 4; ++i2) {
        #pragma unroll
        for (int r = 0; r < 4; ++r) {
            int gm = m0 + wm * 64 + i2 * 16 + rgrp + r;
            int token = gm; float sc = 1.0f;
            if (SCATTER) {
                token = tab[gm];
                if (token < 0) continue;
                sc = rs[token];
            } else if (ROWSCALE) {
                sc = rs[gm];
            }
            #pragma unroll
            for (int j2 = 0; j2 < 4; ++j2) {
                int gn = n0 + wn * 64 + j2 * 16 + colL;
                float v = acc[i2][j2][r] + (bptr ? bptr[gn] : 0.0f);
                if (RELU) v = fmaxf(v, 0.0f);
                if (SCATTER) {
                    long idx = (long)token * N + gn;
                    if (OUTBF16) Cb[idx] = f2bf(addsrc[idx] + v * sc);  // fused cast
                    else         Cf[idx] += v * sc;                     // f32 RMW
                } else {
                    if (ROWSCALE) v *= sc;
                    if (OUTBF16) Cb[(long)gm * N + gn] = f2bf(v);
                    else         Cf[(long)gm * N + gn] = v;
                }
            }
        }
    }
}

// ---------------------------------------------------------------------------
// Dropped-token rows: mixb[row] = bf16(mix[row]) for rows the scatter GEMM
// never touches.
// ---------------------------------------------------------------------------
__global__ __launch_bounds__(256)
void drop_cast_k(const float* __restrict__ mix, unsigned short* __restrict__ mixb,
                 const int* __restrict__ droplist, const int* __restrict__ dropcnt)
{
    const int cnt = *dropcnt;
    for (int i = blockIdx.x; i < cnt; i += gridDim.x) {
        const int tok = droplist[i];
        const float4* src = (const float4*)(mix + (long)tok * HD);
        ushort4* dst = (ushort4*)(mixb + (long)tok * HD);
        const int j = threadIdx.x;          // 256 threads x 4 elems = 1024
        float4 v = src[j];
        ushort4 o;
        o.x = f2bf(v.x); o.y = f2bf(v.y); o.z = f2bf(v.z); o.w = f2bf(v.w);
        dst[j] = o;
    }
}

// ---------------------------------------------------------------------------
// f32 -> bf16 cast (vectorized, grid-stride)
// ---------------------------------------------------------------------------
__global__ __launch_bounds__(256)
void cast_bf16_k(const float* __restrict__ in, unsigned short* __restrict__ out,
                 long n4)
{
    long i = (long)blockIdx.x * 256 + threadIdx.x;
    long stride = (long)gridDim.x * 256;
    for (; i < n4; i += stride) {
        float4 v = ((const float4*)in)[i];
        ushort4 o;
        o.x = f2bf(v.x); o.y = f2bf(v.y); o.z = f2bf(v.z); o.w = f2bf(v.w);
        ((ushort4*)out)[i] = o;
    }
}

// ---------------------------------------------------------------------------
// Transpose + cast: W[K][N] f32 -> Wt[N][K] bf16, 64x64 LDS tiles. z batched.
// ---------------------------------------------------------------------------
__global__ __launch_bounds__(256)
void transpose_cast_k(const float* __restrict__ W, unsigned short* __restrict__ Wt,
                      int K, int N, long wB, long wtB)
{
    const int z = blockIdx.z;
    W  += (long)z * wB;
    Wt += (long)z * wtB;
    __shared__ float tile[64][65];
    const int k0 = blockIdx.x * 64, n0 = blockIdx.y * 64;
    const int c = threadIdx.x & 63, r4 = threadIdx.x >> 6;
    #pragma unroll 4
    for (int it = 0; it < 16; ++it) {
        int row = it * 4 + r4;
        tile[row][c] = W[(long)(k0 + row) * N + n0 + c];
    }
    __syncthreads();
    #pragma unroll 4
    for (int it = 0; it < 16; ++it) {
        int nrow = it * 4 + r4;
        Wt[(long)(n0 + nrow) * K + k0 + c] = f2bf(tile[c][nrow]);
    }
}

// ---------------------------------------------------------------------------
// Fused-bias helpers: out[z][n] = sum_k v[z*vB+k] * W[z*wB + k*HD + n] (+badd)
// init writes badd (or 0); acc atomically adds K-chunk partials. (R13-verified)
// ---------------------------------------------------------------------------
__global__ void vecmat_init_k(const float* __restrict__ badd, long bB,
                              float* __restrict__ out, long oB)
{
    const int z = blockIdx.y;
    const int n = blockIdx.x * 256 + threadIdx.x;
    out[z * oB + n] = badd ? badd[z * bB + n] : 0.0f;
}

__global__ void vecmat_acc_k(const float* __restrict__ v, long vB,
                             const float* __restrict__ W, long wB,
                             float* __restrict__ out, long oB)
{
    const int z = blockIdx.z;
    const int n = blockIdx.x * 256 + threadIdx.x;
    const int kc = blockIdx.y;             // K chunk of 128
    const float* vp = v + z * vB;
    const float* Wp = W + z * wB;
    float acc = 0.f;
    #pragma unroll 8
    for (int k = kc * 128; k < kc * 128 + 128; ++k)
        acc = fmaf(vp[k], Wp[(long)k * HD + n], acc);
    atomicAdd(out + z * oB + n, acc);
}

// ---------------------------------------------------------------------------
// Wsmall: Wg'[H][8] = W_in @ W_gate, Wc'[H][2] = W_in @ W_coef  (f32)
// ---------------------------------------------------------------------------
__global__ __launch_bounds__(256)
void wsmall_k(const float* __restrict__ W_in, const float* __restrict__ W_gate,
              const float* __restrict__ W_coef,
              float* __restrict__ wgp, float* __restrict__ wcp)
{
    const int r = blockIdx.x * 4 + (threadIdx.x >> 6);
    const int lane = threadIdx.x & 63;
    float s[10] = {};
    for (int k = lane; k < HD; k += 64) {
        float a = W_in[(long)r * HD + k];
        const float4* g = (const float4*)(W_gate + (long)k * 8);
        float4 g0 = g[0], g1 = g[1];
        s[0] += a * g0.x; s[1] += a * g0.y; s[2] += a * g0.z; s[3] += a * g0.w;
        s[4] += a * g1.x; s[5] += a * g1.y; s[6] += a * g1.z; s[7] += a * g1.w;
        float2 cv = *(const float2*)(W_coef + (long)k * 2);
        s[8] += a * cv.x; s[9] += a * cv.y;
    }
    #pragma unroll
    for (int off = 32; off > 0; off >>= 1)
        #pragma unroll
        for (int e = 0; e < 10; ++e) s[e] += __shfl_xor(s[e], off);
    if (lane == 0) {
        #pragma unroll
        for (int e = 0; e < 8; ++e) wgp[(long)r * 8 + e] = s[e];
        wcp[(long)r * 2 + 0] = s[8];
        wcp[(long)r * 2 + 1] = s[9];
    }
}

// bg[8] = b_in @ W_gate ; bc[2] = b_in @ W_coef + b_coef
__global__ void gbias_k(const float* __restrict__ b_in, const float* __restrict__ W_gate,
                        const float* __restrict__ W_coef, const float* __restrict__ b_coef,
                        float* __restrict__ bg, float* __restrict__ bc)
{
    const int lane = threadIdx.x;  // 64
    float s[10] = {};
    for (int k = lane; k < HD; k += 64) {
        float a = b_in[k];
        const float4* g = (const float4*)(W_gate + (long)k * 8);
        float4 g0 = g[0], g1 = g[1];
        s[0] += a * g0.x; s[1] += a * g0.y; s[2] += a * g0.z; s[3] += a * g0.w;
        s[4] += a * g1.x; s[5] += a * g1.y; s[6] += a * g1.z; s[7] += a * g1.w;
        float2 cv = *(const float2*)(W_coef + (long)k * 2);
        s[8] += a * cv.x; s[9] += a * cv.y;
    }
    #pragma unroll
    for (int off = 32; off > 0; off >>= 1)
        #pragma unroll
        for (int e = 0; e < 10; ++e) s[e] += __shfl_xor(s[e], off);
    if (lane == 0) {
        #pragma unroll
        for (int e = 0; e < 8; ++e) bg[e] = s[e];
        bc[0] = s[8] + b_coef[0];
        bc[1] = s[9] + b_coef[1];
    }
}

// ---------------------------------------------------------------------------
// Gating from x with fused weights (one wave per token) + fused x->bf16 cast.
// ---------------------------------------------------------------------------
__global__ __launch_bounds__(256)
void gating_k(const float* __restrict__ x,
              const float* __restrict__ Wg,   // [H,8] fused
              const float* __restrict__ Wc,   // [H,2] fused
              const float* __restrict__ bg,   // [8]
              const float* __restrict__ bc,   // [2]
              unsigned short* __restrict__ xb,
              int* __restrict__ eidx,
              float* __restrict__ gval,
              float* __restrict__ coef0,
              float* __restrict__ coef1)
{
    const int tok = (blockIdx.x * 256 + threadIdx.x) >> 6;
    const int lane = threadIdx.x & 63;
    const float* row = x + (long)tok * HD;
    unsigned short* orow = xb + (long)tok * HD;

    float acc[8] = {};
    float c0 = 0.f, c1 = 0.f;
    for (int i = 0; i < HD / 64; ++i) {
        int k = i * 64 + lane;
        float tv = row[k];
        orow[k] = f2bf(tv);                      // fused x -> bf16 (coalesced)
        const float4* wg = (const float4*)(Wg + (long)k * 8);
        float4 w0 = wg[0], w1 = wg[1];
        acc[0] = fmaf(tv, w0.x, acc[0]); acc[1] = fmaf(tv, w0.y, acc[1]);
        acc[2] = fmaf(tv, w0.z, acc[2]); acc[3] = fmaf(tv, w0.w, acc[3]);
        acc[4] = fmaf(tv, w1.x, acc[4]); acc[5] = fmaf(tv, w1.y, acc[5]);
        acc[6] = fmaf(tv, w1.z, acc[6]); acc[7] = fmaf(tv, w1.w, acc[7]);
        float2 wcv = *(const float2*)(Wc + (long)k * 2);
        c0 = fmaf(tv, wcv.x, c0);
        c1 = fmaf(tv, wcv.y, c1);
    }
    #pragma unroll
    for (int off = 32; off > 0; off >>= 1) {
        #pragma unroll
        for (int e = 0; e < 8; ++e) acc[e] += __shfl_xor(acc[e], off);
        c0 += __shfl_xor(c0, off);
        c1 += __shfl_xor(c1, off);
    }
    if (lane == 0) {
        #pragma unroll
        for (int e = 0; e < 8; ++e) acc[e] += bg[e];
        float m = acc[0]; int best = 0;
        #pragma unroll
        for (int e = 1; e < 8; ++e) if (acc[e] > m) { m = acc[e]; best = e; }
        float s = 0.f;
        #pragma unroll
        for (int e = 0; e < 8; ++e) s += expf(acc[e] - m);
        eidx[tok] = best;
        gval[tok] = 1.0f / s;
        float l0 = c0 + bc[0], l1 = c1 + bc[1];
        float mm = fmaxf(l0, l1);
        float e0 = expf(l0 - mm), e1 = expf(l1 - mm);
        float inv = 1.0f / (e0 + e1);
        coef0[tok] = e0 * inv;
        coef1[tok] = e1 * inv;
    }
}

// ---------------------------------------------------------------------------
// Parallel capacity scan, 3 phases (integer-exact, verified round 5).
// ---------------------------------------------------------------------------
__global__ void scan_hist_k(const int* __restrict__ eidx,
                            int* __restrict__ counts,
                            int* __restrict__ idxTab)
{
    const int b = blockIdx.x;          // chunk id, 0..255
    const int lane = threadIdx.x;      // 64
    for (int j = b * 64 + lane; j < NE * CAP; j += NCHUNK * 64)
        idxTab[j] = -1;
    int e = eidx[b * 64 + lane];
    #pragma unroll
    for (int ex = 0; ex < NE; ++ex) {
        unsigned long long msk = __ballot(e == ex);
        if (lane == ex) counts[b * NE + ex] = (int)__popcll(msk);
    }
}

__global__ void scan_offsets_k(const int* __restrict__ counts,
                               int* __restrict__ offsets,
                               int* __restrict__ dropcnt)
{
    const int e = threadIdx.x;         // 64 threads, 8 active
    if (e == 63) *dropcnt = 0;         // runs before scan_fill_k
    if (e < NE) {
        int run = 0;
        for (int b = 0; b < NCHUNK; ++b) {
            offsets[b * NE + e] = run;
            run += counts[b * NE + e];
        }
    }
}

__global__ void scan_fill_k(const int* __restrict__ eidx,
                            const float* __restrict__ gval,
                            const float* __restrict__ coef0,
                            const int* __restrict__ offsets,
                            int* __restrict__ idxTab,
                            float* __restrict__ smoe,
                            int* __restrict__ droplist,
                            int* __restrict__ dropcnt)
{
    const int b = blockIdx.x;
    const int lane = threadIdx.x;
    const int tok = b * 64 + lane;
    int e = eidx[tok];
    unsigned long long below = (lane == 0) ? 0ull : ((~0ull) >> (64 - lane));
    int myrank = 0;
    #pragma unroll
    for (int ex = 0; ex < NE; ++ex) {
        unsigned long long msk = __ballot(e == ex);
        if (e == ex) myrank = (int)__popcll(msk & below) + offsets[b * NE + ex];
    }
    if (myrank < CAP) {
        idxTab[e * CAP + myrank] = tok;
        smoe[tok] = gval[tok] * coef0[tok];
    } else {
        smoe[tok] = 0.0f;
        int di = atomicAdd(dropcnt, 1);    // order varies; content is a set
        droplist[di] = tok;
    }
}

// ---------------------------------------------------------------------------
// Workspace plan (lifetime-aliased; ~112 MB):
//   [0,40Mi):   pre-fusion W1T(16)+Wr1T(2)+Winp(2) — dead after fusion;
//               h(40) overlays from FC1 on
//   [40,58Mi):  WF1T(16)+WFr1T(2)  (fused, live to FC1/res1)
//   [58,78Mi):  W2T(16)+Wr2T(2)+WoutT(2)  (live to k/m)
//   [78,110Mi): res1 (32, written i, read j) then mixb (32, written k, read m)
//   [110Mi..):  small (biases, routing arrays)
//   xb: d_out[0,32Mi) bf16 (written gating, dead after res1);
//   mix: d_out f32 (written j, read k/k2); out: d_out (written m)
// ---------------------------------------------------------------------------
extern "C" void kernel_launch(void* const* d_in, const int* in_sizes, int n_in,
                              void* d_out, int out_size, void* d_ws, size_t ws_size,
                              hipStream_t stream)
{
    const float* x      = (const float*)d_in[0];
    const float* W_in   = (const float*)d_in[1];
    const float* b_in   = (const float*)d_in[2];
    const float* W_gate = (const float*)d_in[3];
    const float* W1     = (const float*)d_in[4];
    const float* b1     = (const float*)d_in[5];
    const float* W2     = (const float*)d_in[6];
    const float* b2     = (const float*)d_in[7];
    const float* Wr1    = (const float*)d_in[8];
    const float* br1    = (const float*)d_in[9];
    const float* Wr2    = (const float*)d_in[10];
    const float* br2    = (const float*)d_in[11];
    const float* W_coef = (const float*)d_in[12];
    const float* b_coef = (const float*)d_in[13];
    const float* W_out  = (const float*)d_in[14];
    const float* b_out  = (const float*)d_in[15];
    float* out = (float*)d_out;

    const size_t MiB = 1024 * 1024;
    char* ws = (char*)d_ws;
    // pre-fusion (dead after fusion GEMM); h overlays [0,40Mi)
    unsigned short* W1T   = (unsigned short*)(ws + 0);         // 16 MiB (z=8)
    unsigned short* Wr1T  = (unsigned short*)(ws + 16 * MiB);  // 2 MiB (A-batch z=8)
    unsigned short* Winp  = (unsigned short*)(ws + 18 * MiB);  // 2 MiB plain cast
    unsigned short* h     = (unsigned short*)(ws + 0);         // 40 MiB overlay
    // fused input-side weights
    unsigned short* WF1T  = (unsigned short*)(ws + 40 * MiB);  // 16 MiB
    unsigned short* WFr1T = (unsigned short*)(ws + 56 * MiB);  // 2 MiB (C-batch z=8)
    // tail weights (R12 path)
    unsigned short* W2T   = (unsigned short*)(ws + 58 * MiB);  // 16 MiB
    unsigned short* Wr2T  = (unsigned short*)(ws + 74 * MiB);  // 2 MiB
    unsigned short* WoutT = (unsigned short*)(ws + 76 * MiB);  // 2 MiB
    unsigned short* res1  = (unsigned short*)(ws + 78 * MiB);  // 32 MiB (i..j)
    unsigned short* mixb  = (unsigned short*)(ws + 78 * MiB);  // 32 MiB (k..m)
    char* sm = ws + 110 * MiB;
    float* wgp  = (float*)(sm);            sm += HD * 8 * 4;
    float* wcp  = (float*)(sm);            sm += HD * 2 * 4;
    float* bg   = (float*)(sm);            sm += 64;
    float* bc   = (float*)(sm);            sm += 64;
    float* bf1  = (float*)(sm);            sm += NE * HD * 4;   // b_in@W1[e]+b1[e]
    float* bfr1 = (float*)(sm);            sm += HD * 4;        // b_in@Wr1+br1
    int*   eidx = (int*)(sm);              sm += T_TOK * 4;
    float* gval = (float*)(sm);            sm += T_TOK * 4;
    float* cf0  = (float*)(sm);            sm += T_TOK * 4;
    float* cf1  = (float*)(sm);            sm += T_TOK * 4;
    float* smoe = (float*)(sm);            sm += T_TOK * 4;
    int* idxTab = (int*)(sm);              sm += NE * CAP * 4;
    int* counts = (int*)(sm);              sm += NCHUNK * NE * 4;
    int* offs   = (int*)(sm);              sm += NCHUNK * NE * 4;
    int* droplist = (int*)(sm);            sm += T_TOK * 4;
    int* dropcnt  = (int*)(sm);            sm += 64;
    unsigned short* xb = (unsigned short*)d_out;   // bf16, dead after res1
    float* mix = out;                               // f32, written j, read k/k2
    (void)ws_size; (void)in_sizes; (void)n_in; (void)out_size;

    const long HD2 = (long)HD * HD;
    dim3 blk(256);
    dim3 blkG(512);
    dim3 gT(16, 16, 1);
    dim3 gT8(16, 16, 8);
    dim3 gBig(HD / 128, T_TOK / 256, 1);   // 8 x 64 = 512 blocks (%8==0)
    dim3 gExp(HD / 128, CAP / 256, NE);    // 8 x 10 x 8 = 640 blocks (%8==0)
    dim3 gFuse(HD / 128, HD / 256, 9);     // 8 x 4 x 9 = 288 blocks (%8==0)

    // 1. weight transposes (bf16 [N][K])
    transpose_cast_k<<<gT8, blk, 0, stream>>>(W1, W1T, HD, HD, HD2, HD2);
    transpose_cast_k<<<gT,  blk, 0, stream>>>(Wr1,   Wr1T,  HD, HD, 0, 0);
    transpose_cast_k<<<gT8, blk, 0, stream>>>(W2, W2T, HD, HD, HD2, HD2);
    transpose_cast_k<<<gT,  blk, 0, stream>>>(Wr2,   Wr2T,  HD, HD, 0, 0);
    transpose_cast_k<<<gT,  blk, 0, stream>>>(W_out, WoutT, HD, HD, 0, 0);
    // 2. plain cast — fusion Bt operand
    cast_bf16_k<<<512, blk, 0, stream>>>(W_in, Winp, HD2 / 4);
    // 3. fused gating weights + biases (f32 routing path)
    wsmall_k<<<HD / 4, blk, 0, stream>>>(W_in, W_gate, W_coef, wgp, wcp);
    gbias_k<<<1, 64, 0, stream>>>(b_in, W_gate, W_coef, b_coef, bg, bc);
    // 4. fused biases bf1, bfr1 (R13-verified kernels)
    vecmat_init_k<<<dim3(HD/256, NE), blk, 0, stream>>>(b1, HD, bf1, HD);
    vecmat_acc_k <<<dim3(HD/256, 8, NE), blk, 0, stream>>>(b_in, 0, W1, HD2, bf1, HD);
    vecmat_init_k<<<dim3(HD/256, 1), blk, 0, stream>>>(br1, 0, bfr1, 0);
    vecmat_acc_k <<<dim3(HD/256, 8, 1), blk, 0, stream>>>(b_in, 0, Wr1, 0, bfr1, 0);
    // 5. gating from x (f32 routing) + fused x->bf16 cast into d_out
    gating_k<<<T_TOK / 4, blk, 0, stream>>>(x, wgp, wcp, bg, bc, xb,
                                            eidx, gval, cf0, cf1);
    // 6. parallel capacity scan (+ dropped-token list)
    scan_hist_k<<<NCHUNK, 64, 0, stream>>>(eidx, counts, idxTab);
    scan_offsets_k<<<1, 64, 0, stream>>>(counts, offs, dropcnt);
    scan_fill_k<<<NCHUNK, 64, 0, stream>>>(eidx, gval, cf0, offs, idxTab, smoe,
                                           droplist, dropcnt);
    // 7. input-side weight fusion: [WF1T(8), WFr1T] = [W1T(8), Wr1T] x Winp
    //    (z=9 batched; orientation verified in R13's passing run)
    gemm_bf16_k<false, false, false, false, true><<<gFuse, blkG, 0, stream>>>(
        W1T, Winp, nullptr, WF1T, HD, HD, HD, nullptr, nullptr, nullptr,
        HD2, 0, 0, 0, HD2);
    // 9. FC1: h[e] = relu(gather(xb) @ WF1[e] + bf1[e])  bf16, empty-tile exit
    gemm_bf16_k<true, true, false, false, true><<<gExp, blkG, 0, stream>>>(
        xb, WF1T, bf1, h, CAP, HD, HD, idxTab, nullptr, nullptr,
        0, HD2, HD, CAP, (long)CAP * HD);
    // 10. res1 = relu(xb @ WFr1 + bfr1)   bf16
    gemm_bf16_k<false, true, false, false, true><<<gBig, blkG, 0, stream>>>(
        xb, WFr1T, bfr1, res1, T_TOK, HD, HD, nullptr, nullptr, nullptr,
        0, 0, 0, 0, 0);
    // 11. j: mix = (res1 @ Wr2 + br2) * cf1[row]   f32 -> d_out (kills xb)
    gemm_bf16_k<false, false, true, false, false><<<gBig, blkG, 0, stream>>>(
        res1, Wr2T, br2, mix, T_TOK, HD, HD, nullptr, cf1, nullptr,
        0, 0, 0, 0, 0);
    // 12. k: mixb[tok] = bf16(mix[tok] + (h[e]@W2[e]+b2[e])*smoe[tok])
    //     fused cast, empty-tile exit
    gemm_bf16_k<false, false, false, true, true><<<gExp, blkG, 0, stream>>>(
        h, W2T, b2, mixb, CAP, HD, HD, idxTab, smoe, mix,
        (long)CAP * HD, HD2, HD, CAP, 0);
    // 13. k2: dropped-token rows: mixb = bf16(mix)
    drop_cast_k<<<256, blk, 0, stream>>>(mix, mixb, droplist, dropcnt);
    // 14. m: out = mixb @ W_out + b_out   f32 -> d_out
    gemm_bf16_k<false, false, false, false, false><<<gBig, blkG, 0, stream>>>(
        mixb, WoutT, b_out, out, T_TOK, HD, HD, nullptr, nullptr, nullptr,
        0, 0, 0, 0, 0);
}

// Round 15
// 446.920 us; speedup vs baseline: 1.0291x; 1.0282x over previous
//
#include <hip/hip_runtime.h>
#include <cstdint>

// Problem constants (static per reference)
#define T_TOK 16384     // B*S
#define HD    1024      // H
#define NE    8         // experts
#define CAP   2560      // ceil(1.25*T/E)
#define NCHUNK (T_TOK / 64)   // 256

typedef __attribute__((ext_vector_type(4))) float f32x4;
typedef __attribute__((ext_vector_type(8))) short bf16x8;   // 8 bf16 = 4 VGPRs

__device__ __forceinline__ unsigned short f2bf(float f) {
    union { float f; unsigned u; } x{f};
    unsigned r = x.u + 0x7FFF + ((x.u >> 16) & 1);   // RNE
    return (unsigned short)(r >> 16);
}

__device__ __forceinline__ void gload_lds16(const unsigned short* g, unsigned short* l) {
    __builtin_amdgcn_global_load_lds(
        (const __attribute__((address_space(1))) void*)g,
        (__attribute__((address_space(3))) void*)l, 16, 0, 0);
}

// ---------------------------------------------------------------------------
// bf16 MFMA GEMM: C[M,N] = op(A[M,K] @ Bt[N,K]^T + bias[N])
// R15 = R12 verbatim (best measured: 404.6us total, ~80us/GEMM):
// 256x128 tile, BK=64, 8 waves (4m x 2n), SINGLE-buffer 2-barrier loop.
// All deviations tried (R7/R8/R11 pipelining, R13/R14 weight fusion)
// regressed; this is the measured optimum for this decomposition.
// - XCD-aware bijective block swizzle (FETCH 206->70MB, R6).
// - 128B LDS rows + 16B-chunk XOR swizzle, pre-swizzled global source +
//   swizzled ds_read, linear gload_lds dest (0 bank conflicts, R6).
// - Empty-tile early-exit for expert GEMMs (slots fill contiguously, R12).
// - SCATTER+OUTBF16: fused bf16 C = f2bf(addsrc + v*sc) (R10).
// ---------------------------------------------------------------------------
template<bool GATHER, bool RELU, bool ROWSCALE, bool SCATTER, bool OUTBF16>
__global__ __launch_bounds__(512)
void gemm_bf16_k(const unsigned short* __restrict__ A,
                 const unsigned short* __restrict__ Bt,
                 const float* __restrict__ bias,
                 void* __restrict__ Cv,
                 int M, int N, int K,
                 const int* __restrict__ idxTab,
                 const float* __restrict__ rs,
                 const float* __restrict__ addsrc,
                 long aB, long bB, long biasB, long tabB, long cB)
{
    // ---- XCD-aware remap: XCD c gets contiguous logical chunk ----
    const int nx = gridDim.x, ny = gridDim.y;
    long nwg = (long)nx * ny * gridDim.z;
    long flat = blockIdx.x + (long)nx * (blockIdx.y + (long)ny * blockIdx.z);
    long cpx = nwg >> 3;                       // nwg % 8 == 0 by construction
    long swz = (flat & 7) * cpx + (flat >> 3);
    const int bx = (int)(swz % nx);
    const int by = (int)((swz / nx) % ny);
    const int bz = (int)(swz / ((long)nx * ny));

    A  += (long)bz * aB;
    Bt += (long)bz * bB;
    const float* bptr = bias ? bias + (long)bz * biasB : nullptr;
    const int* tab = idxTab ? idxTab + (long)bz * tabB : nullptr;
    float*          Cf = (float*)Cv + (long)bz * cB;
    unsigned short* Cb = (unsigned short*)Cv + (long)bz * cB;

    const int m0 = by * 256, n0 = bx * 128;

    // empty-tile early-exit (uniform across block; before any barrier)
    if ((GATHER || SCATTER) && tab[m0] < 0) return;

    __shared__ unsigned short As[256][64];   // 32 KB, row = m
    __shared__ unsigned short Bs[128][64];   // 16 KB, row = n  (48 KB total)

    const int tid  = threadIdx.x;
    const int wv   = tid >> 6;               // 0..7
    const int lane = tid & 63;

    // staging: issue = 8 rows x 128 B = 1024 B = 64 lanes x 16 B.
    const int srow = lane >> 3;
    const int schk = lane & 7;

    const unsigned short* aSrc[4];           // wave stages A rows wv*32..+31
    const unsigned short* bSrc[2];           // wave stages B rows wv*16..+15
    #pragma unroll
    for (int i = 0; i < 4; ++i) {
        int lrow = wv * 32 + i * 8 + srow;          // 0..255
        int scol = ((schk ^ (lrow & 7)) * 8);       // swizzled col (elems)
        long sr;
        if (GATHER) { int tr = tab[m0 + lrow]; sr = tr < 0 ? 0 : tr; }
        else        sr = m0 + lrow;
        aSrc[i] = A + sr * (long)K + scol;
    }
    #pragma unroll
    for (int i = 0; i < 2; ++i) {
        int lrow = wv * 16 + i * 8 + srow;          // 0..127
        int scol = ((schk ^ (lrow & 7)) * 8);
        bSrc[i] = Bt + (long)(n0 + lrow) * K + scol;
    }

    f32x4 acc[4][4] = {};
    const int wm = wv >> 1, wn = wv & 1;     // 4 x 2 wave grid
    const int fr = lane & 15, kg = lane >> 4;

    for (int k0 = 0; k0 < K; k0 += 64) {
        __syncthreads();                     // prev tile fully consumed
        #pragma unroll
        for (int i = 0; i < 4; ++i)
            gload_lds16(aSrc[i] + k0, &As[wv * 32 + i * 8][0]);
        #pragma unroll
        for (int i = 0; i < 2; ++i)
            gload_lds16(bSrc[i] + k0, &Bs[wv * 16 + i * 8][0]);
        __syncthreads();                     // vmcnt(0) drained here

        #pragma unroll
        for (int kk = 0; kk < 2; ++kk) {     // two K=32 halves of BK=64
            bf16x8 af[4], bfr[4];
            #pragma unroll
            for (int i2 = 0; i2 < 4; ++i2) {
                int R = wm * 64 + i2 * 16 + fr;
                af[i2] = *(const bf16x8*)&As[R][((kk * 4 + kg) ^ (R & 7)) * 8];
            }
            #pragma unroll
            for (int j2 = 0; j2 < 4; ++j2) {
                int R = wn * 64 + j2 * 16 + fr;
                bfr[j2] = *(const bf16x8*)&Bs[R][((kk * 4 + kg) ^ (R & 7)) * 8];
            }
            #pragma unroll
            for (int i2 = 0; i2 < 4; ++i2)
                #pragma unroll
                for (int j2 = 0; j2 < 4; ++j2)
                    acc[i2][j2] = __builtin_amdgcn_mfma_f32_16x16x32_bf16(
                        af[i2], bfr[j2], acc[i2][j2], 0, 0, 0);
        }
    }

    // epilogue: C/D layout col = lane&15, row = (lane>>4)*4 + r
    const int colL = lane & 15, rgrp = (lane >> 4) * 4;
    #pragma unroll
    for (int i2 = 0; i2 < 4; ++i2) {
        #pragma unroll
        for (int r = 0; r < 4; ++r) {
            int gm = m0 + wm * 64 + i2 * 16 + rgrp + r;
            int token = gm; float sc = 1.0f;
            if (SCATTER) {
                token = tab[gm];
                if (token < 0) continue;
                sc = rs[token];
            } else if (ROWSCALE) {
                sc = rs[gm];
            }
            #pragma unroll
            for (int j2 = 0; j2 < 4; ++j2) {
                int gn = n0 + wn * 64 + j2 * 16 + colL;
                float v = acc[i2][j2][r] + (bptr ? bptr[gn] : 0.0f);
                if (RELU) v = fmaxf(v, 0.0f);
                if (SCATTER) {
                    long idx = (long)token * N + gn;
                    if (OUTBF16) Cb[idx] = f2bf(addsrc[idx] + v * sc);  // fused cast
                    else         Cf[idx] += v * sc;                     // f32 RMW
                } else {
                    if (ROWSCALE) v *= sc;
                    if (OUTBF16) Cb[(long)gm * N + gn] = f2bf(v);
                    else         Cf[(long)gm * N + gn] = v;
                }
            }
        }
    }
}

// ---------------------------------------------------------------------------
// Dropped-token rows: mixb[row] = bf16(mix[row]) for rows never touched by
// the scatter GEMM.
// ---------------------------------------------------------------------------
__global__ __launch_bounds__(256)
void drop_cast_k(const float* __restrict__ mix, unsigned short* __restrict__ mixb,
                 const int* __restrict__ droplist, const int* __restrict__ dropcnt)
{
    const int cnt = *dropcnt;
    for (int i = blockIdx.x; i < cnt; i += gridDim.x) {
        const int tok = droplist[i];
        const float4* src = (const float4*)(mix + (long)tok * HD);
        ushort4* dst = (ushort4*)(mixb + (long)tok * HD);
        const int j = threadIdx.x;          // 256 threads x 4 elems = 1024
        float4 v = src[j];
        ushort4 o;
        o.x = f2bf(v.x); o.y = f2bf(v.y); o.z = f2bf(v.z); o.w = f2bf(v.w);
        dst[j] = o;
    }
}

// ---------------------------------------------------------------------------
// Transpose + cast: W[K][N] f32 -> Wt[N][K] bf16, 64x64 LDS tiles. z batched.
// ---------------------------------------------------------------------------
__global__ __launch_bounds__(256)
void transpose_cast_k(const float* __restrict__ W, unsigned short* __restrict__ Wt,
                      int K, int N, long wB, long wtB)
{
    const int z = blockIdx.z;
    W  += (long)z * wB;
    Wt += (long)z * wtB;
    __shared__ float tile[64][65];
    const int k0 = blockIdx.x * 64, n0 = blockIdx.y * 64;
    const int c = threadIdx.x & 63, r4 = threadIdx.x >> 6;
    #pragma unroll 4
    for (int it = 0; it < 16; ++it) {
        int row = it * 4 + r4;
        tile[row][c] = W[(long)(k0 + row) * N + n0 + c];
    }
    __syncthreads();
    #pragma unroll 4
    for (int it = 0; it < 16; ++it) {
        int nrow = it * 4 + r4;
        Wt[(long)(n0 + nrow) * K + k0 + c] = f2bf(tile[c][nrow]);
    }
}

// ---------------------------------------------------------------------------
// Wsmall: Wg'[H][8] = W_in @ W_gate, Wc'[H][2] = W_in @ W_coef  (f32)
// ---------------------------------------------------------------------------
__global__ __launch_bounds__(256)
void wsmall_k(const float* __restrict__ W_in, const float* __restrict__ W_gate,
              const float* __restrict__ W_coef,
              float* __restrict__ wgp, float* __restrict__ wcp)
{
    const int r = blockIdx.x * 4 + (threadIdx.x >> 6);
    const int lane = threadIdx.x & 63;
    float s[10] = {};
    for (int k = lane; k < HD; k += 64) {
        float a = W_in[(long)r * HD + k];
        const float4* g = (const float4*)(W_gate + (long)k * 8);
        float4 g0 = g[0], g1 = g[1];
        s[0] += a * g0.x; s[1] += a * g0.y; s[2] += a * g0.z; s[3] += a * g0.w;
        s[4] += a * g1.x; s[5] += a * g1.y; s[6] += a * g1.z; s[7] += a * g1.w;
        float2 cv = *(const float2*)(W_coef + (long)k * 2);
        s[8] += a * cv.x; s[9] += a * cv.y;
    }
    #pragma unroll
    for (int off = 32; off > 0; off >>= 1)
        #pragma unroll
        for (int e = 0; e < 10; ++e) s[e] += __shfl_xor(s[e], off);
    if (lane == 0) {
        #pragma unroll
        for (int e = 0; e < 8; ++e) wgp[(long)r * 8 + e] = s[e];
        wcp[(long)r * 2 + 0] = s[8];
        wcp[(long)r * 2 + 1] = s[9];
    }
}

// bg[8] = b_in @ W_gate ; bc[2] = b_in @ W_coef + b_coef
__global__ void gbias_k(const float* __restrict__ b_in, const float* __restrict__ W_gate,
                        const float* __restrict__ W_coef, const float* __restrict__ b_coef,
                        float* __restrict__ bg, float* __restrict__ bc)
{
    const int lane = threadIdx.x;  // 64
    float s[10] = {};
    for (int k = lane; k < HD; k += 64) {
        float a = b_in[k];
        const float4* g = (const float4*)(W_gate + (long)k * 8);
        float4 g0 = g[0], g1 = g[1];
        s[0] += a * g0.x; s[1] += a * g0.y; s[2] += a * g0.z; s[3] += a * g0.w;
        s[4] += a * g1.x; s[5] += a * g1.y; s[6] += a * g1.z; s[7] += a * g1.w;
        float2 cv = *(const float2*)(W_coef + (long)k * 2);
        s[8] += a * cv.x; s[9] += a * cv.y;
    }
    #pragma unroll
    for (int off = 32; off > 0; off >>= 1)
        #pragma unroll
        for (int e = 0; e < 10; ++e) s[e] += __shfl_xor(s[e], off);
    if (lane == 0) {
        #pragma unroll
        for (int e = 0; e < 8; ++e) bg[e] = s[e];
        bc[0] = s[8] + b_coef[0];
        bc[1] = s[9] + b_coef[1];
    }
}

// ---------------------------------------------------------------------------
// Gating from x with fused weights (one wave per token) + fused x->bf16 cast.
// ---------------------------------------------------------------------------
__global__ __launch_bounds__(256)
void gating_k(const float* __restrict__ x,
              const float* __restrict__ Wg,   // [H,8] fused
              const float* __restrict__ Wc,   // [H,2] fused
              const float* __restrict__ bg,   // [8]
              const float* __restrict__ bc,   // [2]
              unsigned short* __restrict__ xb,
              int* __restrict__ eidx,
              float* __restrict__ gval,
              float* __restrict__ coef0,
              float* __restrict__ coef1)
{
    const int tok = (blockIdx.x * 256 + threadIdx.x) >> 6;
    const int lane = threadIdx.x & 63;
    const float* row = x + (long)tok * HD;
    unsigned short* orow = xb + (long)tok * HD;

    float acc[8] = {};
    float c0 = 0.f, c1 = 0.f;
    for (int i = 0; i < HD / 64; ++i) {
        int k = i * 64 + lane;
        float tv = row[k];
        orow[k] = f2bf(tv);                      // fused x -> bf16 (coalesced)
        const float4* wg = (const float4*)(Wg + (long)k * 8);
        float4 w0 = wg[0], w1 = wg[1];
        acc[0] = fmaf(tv, w0.x, acc[0]); acc[1] = fmaf(tv, w0.y, acc[1]);
        acc[2] = fmaf(tv, w0.z, acc[2]); acc[3] = fmaf(tv, w0.w, acc[3]);
        acc[4] = fmaf(tv, w1.x, acc[4]); acc[5] = fmaf(tv, w1.y, acc[5]);
        acc[6] = fmaf(tv, w1.z, acc[6]); acc[7] = fmaf(tv, w1.w, acc[7]);
        float2 wcv = *(const float2*)(Wc + (long)k * 2);
        c0 = fmaf(tv, wcv.x, c0);
        c1 = fmaf(tv, wcv.y, c1);
    }
    #pragma unroll
    for (int off = 32; off > 0; off >>= 1) {
        #pragma unroll
        for (int e = 0; e < 8; ++e) acc[e] += __shfl_xor(acc[e], off);
        c0 += __shfl_xor(c0, off);
        c1 += __shfl_xor(c1, off);
    }
    if (lane == 0) {
        #pragma unroll
        for (int e = 0; e < 8; ++e) acc[e] += bg[e];
        float m = acc[0]; int best = 0;
        #pragma unroll
        for (int e = 1; e < 8; ++e) if (acc[e] > m) { m = acc[e]; best = e; }
        float s = 0.f;
        #pragma unroll
        for (int e = 0; e < 8; ++e) s += expf(acc[e] - m);
        eidx[tok] = best;
        gval[tok] = 1.0f / s;
        float l0 = c0 + bc[0], l1 = c1 + bc[1];
        float mm = fmaxf(l0, l1);
        float e0 = expf(l0 - mm), e1 = expf(l1 - mm);
        float inv = 1.0f / (e0 + e1);
        coef0[tok] = e0 * inv;
        coef1[tok] = e1 * inv;
    }
}

// ---------------------------------------------------------------------------
// Parallel capacity scan, 3 phases (integer-exact, verified round 5).
// ---------------------------------------------------------------------------
__global__ void scan_hist_k(const int* __restrict__ eidx,
                            int* __restrict__ counts,
                            int* __restrict__ idxTab)
{
    const int b = blockIdx.x;          // chunk id, 0..255
    const int lane = threadIdx.x;      // 64
    for (int j = b * 64 + lane; j < NE * CAP; j += NCHUNK * 64)
        idxTab[j] = -1;
    int e = eidx[b * 64 + lane];
    #pragma unroll
    for (int ex = 0; ex < NE; ++ex) {
        unsigned long long msk = __ballot(e == ex);
        if (lane == ex) counts[b * NE + ex] = (int)__popcll(msk);
    }
}

__global__ void scan_offsets_k(const int* __restrict__ counts,
                               int* __restrict__ offsets,
                               int* __restrict__ dropcnt)
{
    const int e = threadIdx.x;         // 64 threads, 8 active
    if (e == 63) *dropcnt = 0;         // runs before scan_fill_k
    if (e < NE) {
        int run = 0;
        for (int b = 0; b < NCHUNK; ++b) {
            offsets[b * NE + e] = run;
            run += counts[b * NE + e];
        }
    }
}

__global__ void scan_fill_k(const int* __restrict__ eidx,
                            const float* __restrict__ gval,
                            const float* __restrict__ coef0,
                            const int* __restrict__ offsets,
                            int* __restrict__ idxTab,
                            float* __restrict__ smoe,
                            int* __restrict__ droplist,
                            int* __restrict__ dropcnt)
{
    const int b = blockIdx.x;
    const int lane = threadIdx.x;
    const int tok = b * 64 + lane;
    int e = eidx[tok];
    unsigned long long below = (lane == 0) ? 0ull : ((~0ull) >> (64 - lane));
    int myrank = 0;
    #pragma unroll
    for (int ex = 0; ex < NE; ++ex) {
        unsigned long long msk = __ballot(e == ex);
        if (e == ex) myrank = (int)__popcll(msk & below) + offsets[b * NE + ex];
    }
    if (myrank < CAP) {
        idxTab[e * CAP + myrank] = tok;
        smoe[tok] = gval[tok] * coef0[tok];
    } else {
        smoe[tok] = 0.0f;
        int di = atomicAdd(dropcnt, 1);    // order varies; content is a set
        droplist[di] = tok;
    }
}

// ---------------------------------------------------------------------------
// Workspace plan (lifetime-aliased; ~135 MB):
//   slotA [0,32Mi):   W1T then res1 then mixb
//   h     [32,72Mi);  t_b [72,104Mi); W2T [104,120Mi);
//   WinT/Wr1T/Wr2T/WoutT [120..128Mi); small [128Mi..)
//   xb: d_out[0,32Mi);  mix: d_out f32 (read-only after j);  out: d_out
// ---------------------------------------------------------------------------
extern "C" void kernel_launch(void* const* d_in, const int* in_sizes, int n_in,
                              void* d_out, int out_size, void* d_ws, size_t ws_size,
                              hipStream_t stream)
{
    const float* x      = (const float*)d_in[0];
    const float* W_in   = (const float*)d_in[1];
    const float* b_in   = (const float*)d_in[2];
    const float* W_gate = (const float*)d_in[3];
    const float* W1     = (const float*)d_in[4];
    const float* b1     = (const float*)d_in[5];
    const float* W2     = (const float*)d_in[6];
    const float* b2     = (const float*)d_in[7];
    const float* Wr1    = (const float*)d_in[8];
    const float* br1    = (const float*)d_in[9];
    const float* Wr2    = (const float*)d_in[10];
    const float* br2    = (const float*)d_in[11];
    const float* W_coef = (const float*)d_in[12];
    const float* b_coef = (const float*)d_in[13];
    const float* W_out  = (const float*)d_in[14];
    const float* b_out  = (const float*)d_in[15];
    float* out = (float*)d_out;

    const size_t MiB = 1024 * 1024;
    char* ws = (char*)d_ws;
    unsigned short* W1T  = (unsigned short*)(ws + 0);          // 16 MiB
    unsigned short* res1 = (unsigned short*)(ws + 0);          // 32 MiB (after FC1)
    unsigned short* mixb = (unsigned short*)(ws + 0);          // 32 MiB (after res-mix)
    unsigned short* h    = (unsigned short*)(ws + 32 * MiB);   // 40 MiB
    unsigned short* t_b  = (unsigned short*)(ws + 72 * MiB);   // 32 MiB
    unsigned short* W2T  = (unsigned short*)(ws + 104 * MiB);  // 16 MiB
    unsigned short* WinT = (unsigned short*)(ws + 120 * MiB);  // 2 MiB
    unsigned short* Wr1T = (unsigned short*)(ws + 122 * MiB);  // 2 MiB
    unsigned short* Wr2T = (unsigned short*)(ws + 124 * MiB);  // 2 MiB
    unsigned short* WoutT= (unsigned short*)(ws + 126 * MiB);  // 2 MiB
    char* sm = ws + 128 * MiB;
    float* wgp  = (float*)(sm);            sm += HD * 8 * 4;
    float* wcp  = (float*)(sm);            sm += HD * 2 * 4;
    float* bg   = (float*)(sm);            sm += 64;
    float* bc   = (float*)(sm);            sm += 64;
    int*   eidx = (int*)(sm);              sm += T_TOK * 4;
    float* gval = (float*)(sm);            sm += T_TOK * 4;
    float* cf0  = (float*)(sm);            sm += T_TOK * 4;
    float* cf1  = (float*)(sm);            sm += T_TOK * 4;
    float* smoe = (float*)(sm);            sm += T_TOK * 4;
    int* idxTab = (int*)(sm);              sm += NE * CAP * 4;
    int* counts = (int*)(sm);              sm += NCHUNK * NE * 4;
    int* offs   = (int*)(sm);              sm += NCHUNK * NE * 4;
    int* droplist = (int*)(sm);            sm += T_TOK * 4;
    int* dropcnt  = (int*)(sm);            sm += 64;
    unsigned short* xb = (unsigned short*)d_out;   // 32 MiB, dies after f
    float* mix = out;                               // f32, written j, read k/m
    (void)ws_size; (void)in_sizes; (void)n_in; (void)out_size;

    dim3 blk(256);
    dim3 blkG(512);
    dim3 gT(16, 16, 1);
    dim3 gT8(16, 16, 8);
    dim3 gBig(HD / 128, T_TOK / 256, 1);   // 8 x 64 = 512 blocks (%8==0)
    dim3 gExp(HD / 128, CAP / 256, NE);    // 8 x 10 x 8 = 640 blocks (%8==0)

    // b. weight transposes (bf16 [N][K])
    transpose_cast_k<<<gT,  blk, 0, stream>>>(W_in,  WinT,  HD, HD, 0, 0);
    transpose_cast_k<<<gT,  blk, 0, stream>>>(Wr1,   Wr1T,  HD, HD, 0, 0);
    transpose_cast_k<<<gT,  blk, 0, stream>>>(Wr2,   Wr2T,  HD, HD, 0, 0);
    transpose_cast_k<<<gT,  blk, 0, stream>>>(W_out, WoutT, HD, HD, 0, 0);
    transpose_cast_k<<<gT8, blk, 0, stream>>>(W1, W1T, HD, HD, (long)HD * HD, (long)HD * HD);
    transpose_cast_k<<<gT8, blk, 0, stream>>>(W2, W2T, HD, HD, (long)HD * HD, (long)HD * HD);
    // c. fused gating weights (f32)
    wsmall_k<<<HD / 4, blk, 0, stream>>>(W_in, W_gate, W_coef, wgp, wcp);
    gbias_k<<<1, 64, 0, stream>>>(b_in, W_gate, W_coef, b_coef, bg, bc);
    // d. gating from x (f32 routing path) + fused x->bf16 cast
    gating_k<<<T_TOK / 4, blk, 0, stream>>>(x, wgp, wcp, bg, bc, xb,
                                            eidx, gval, cf0, cf1);
    // e. parallel capacity scan (+ dropped-token list)
    scan_hist_k<<<NCHUNK, 64, 0, stream>>>(eidx, counts, idxTab);
    scan_offsets_k<<<1, 64, 0, stream>>>(counts, offs, dropcnt);
    scan_fill_k<<<NCHUNK, 64, 0, stream>>>(eidx, gval, cf0, offs, idxTab, smoe,
                                           droplist, dropcnt);
    // f. t_b = bf16(xb @ W_in + b_in)
    gemm_bf16_k<false, false, false, false, true><<<gBig, blkG, 0, stream>>>(
        xb, WinT, b_in, t_b, T_TOK, HD, HD, nullptr, nullptr, nullptr,
        0, 0, 0, 0, 0);
    // h. h[e] = relu(gather(t_b) @ W1[e] + b1[e])   bf16 out, empty-tile exit
    gemm_bf16_k<true, true, false, false, true><<<gExp, blkG, 0, stream>>>(
        t_b, W1T, b1, h, CAP, HD, HD, idxTab, nullptr, nullptr,
        0, (long)HD * HD, HD, CAP, (long)CAP * HD);
    // i. res1 = relu(t_b @ Wr1 + br1)   bf16 out (overlays W1T slot)
    gemm_bf16_k<false, true, false, false, true><<<gBig, blkG, 0, stream>>>(
        t_b, Wr1T, br1, res1, T_TOK, HD, HD, nullptr, nullptr, nullptr,
        0, 0, 0, 0, 0);
    // j. mix = (res1 @ Wr2 + br2) * cf1[row]   f32 -> d_out
    gemm_bf16_k<false, false, true, false, false><<<gBig, blkG, 0, stream>>>(
        res1, Wr2T, br2, mix, T_TOK, HD, HD, nullptr, cf1, nullptr,
        0, 0, 0, 0, 0);
    // k. mixb[tok] = bf16(mix[tok] + (h[e]@W2[e]+b2[e])*smoe[tok])  fused cast,
    //    empty-tile exit
    gemm_bf16_k<false, false, false, true, true><<<gExp, blkG, 0, stream>>>(
        h, W2T, b2, mixb, CAP, HD, HD, idxTab, smoe, mix,
        (long)CAP * HD, (long)HD * HD, HD, CAP, 0);
    // k2. dropped-token rows: mixb = bf16(mix)
    drop_cast_k<<<256, blk, 0, stream>>>(mix, mixb, droplist, dropcnt);
    // m. out = mixb @ W_out + b_out   f32 -> d_out
    gemm_bf16_k<false, false, false, false, false><<<gBig, blkG, 0, stream>>>(
        mixb, WoutT, b_out, out, T_TOK, HD, HD, nullptr, nullptr, nullptr,
        0, 0, 0, 0, 0);
}

// Round 16
// 443.211 us; speedup vs baseline: 1.0377x; 1.0084x over previous
//
#include <hip/hip_runtime.h>
#include <cstdint>

// Problem constants (static per reference)
#define T_TOK 16384     // B*S
#define HD    1024      // H
#define NE    8         // experts
#define CAP   2560      // ceil(1.25*T/E)
#define NCHUNK (T_TOK / 64)   // 256

typedef __attribute__((ext_vector_type(4))) float f32x4;
typedef __attribute__((ext_vector_type(8))) short bf16x8;   // 8 bf16 = 4 VGPRs

__device__ __forceinline__ unsigned short f2bf(float f) {
    union { float f; unsigned u; } x{f};
    unsigned r = x.u + 0x7FFF + ((x.u >> 16) & 1);   // RNE
    return (unsigned short)(r >> 16);
}

__device__ __forceinline__ float bf2f(unsigned short b) {
    union { unsigned u; float f; } x;
    x.u = ((unsigned)b) << 16;
    return x.f;
}

__device__ __forceinline__ void gload_lds16(const unsigned short* g, unsigned short* l) {
    __builtin_amdgcn_global_load_lds(
        (const __attribute__((address_space(1))) void*)g,
        (__attribute__((address_space(3))) void*)l, 16, 0, 0);
}

// ---------------------------------------------------------------------------
// bf16 MFMA GEMM: C[M,N] = op(A[M,K] @ Bt[N,K]^T + bias[N])
// R12 structure (measured local optimum across R6..R15; R7/R8/R11 pipelining
// and R13/R14 weight-fusion variants all regressed):
// 256x128 tile, BK=64, 8 waves (4m x 2n), SINGLE-buffer 2-barrier loop.
// - XCD-aware bijective block swizzle (FETCH 206->70MB, R6).
// - 128B LDS rows + 16B-chunk XOR swizzle, pre-swizzled global source +
//   swizzled ds_read, linear gload_lds dest (0 bank conflicts, R6).
// - Empty-tile early-exit for expert GEMMs (slots fill contiguously, R12).
// Epilogues:
//   RELU:              v = max(acc+bias, 0)
//   ROWSCALE:          v = rs[m]*(acc+bias)
//   SCATTER (+OUTBF16): tok=tab[m]; skip<0; in-place bf16 RMW:
//                      Cb[tok] = f2bf(bf2f(Cb[tok]) + v*rs[tok])   (R16)
//   SCATTER (f32):     Cf[tok] += v*rs[tok]
//   OUTBF16:           bf16 store else f32
// ---------------------------------------------------------------------------
template<bool GATHER, bool RELU, bool ROWSCALE, bool SCATTER, bool OUTBF16>
__global__ __launch_bounds__(512)
void gemm_bf16_k(const unsigned short* __restrict__ A,
                 const unsigned short* __restrict__ Bt,
                 const float* __restrict__ bias,
                 void* __restrict__ Cv,
                 int M, int N, int K,
                 const int* __restrict__ idxTab,
                 const float* __restrict__ rs,
                 long aB, long bB, long biasB, long tabB, long cB)
{
    // ---- XCD-aware remap: XCD c gets contiguous logical chunk ----
    const int nx = gridDim.x, ny = gridDim.y;
    long nwg = (long)nx * ny * gridDim.z;
    long flat = blockIdx.x + (long)nx * (blockIdx.y + (long)ny * blockIdx.z);
    long cpx = nwg >> 3;                       // nwg % 8 == 0 by construction
    long swz = (flat & 7) * cpx + (flat >> 3);
    const int bx = (int)(swz % nx);
    const int by = (int)((swz / nx) % ny);
    const int bz = (int)(swz / ((long)nx * ny));

    A  += (long)bz * aB;
    Bt += (long)bz * bB;
    const float* bptr = bias ? bias + (long)bz * biasB : nullptr;
    const int* tab = idxTab ? idxTab + (long)bz * tabB : nullptr;
    float*          Cf = (float*)Cv + (long)bz * cB;
    unsigned short* Cb = (unsigned short*)Cv + (long)bz * cB;

    const int m0 = by * 256, n0 = bx * 128;

    // empty-tile early-exit (uniform across block; before any barrier)
    if ((GATHER || SCATTER) && tab[m0] < 0) return;

    __shared__ unsigned short As[256][64];   // 32 KB, row = m
    __shared__ unsigned short Bs[128][64];   // 16 KB, row = n  (48 KB total)

    const int tid  = threadIdx.x;
    const int wv   = tid >> 6;               // 0..7
    const int lane = tid & 63;

    // staging: issue = 8 rows x 128 B = 1024 B = 64 lanes x 16 B.
    const int srow = lane >> 3;
    const int schk = lane & 7;

    const unsigned short* aSrc[4];           // wave stages A rows wv*32..+31
    const unsigned short* bSrc[2];           // wave stages B rows wv*16..+15
    #pragma unroll
    for (int i = 0; i < 4; ++i) {
        int lrow = wv * 32 + i * 8 + srow;          // 0..255
        int scol = ((schk ^ (lrow & 7)) * 8);       // swizzled col (elems)
        long sr;
        if (GATHER) { int tr = tab[m0 + lrow]; sr = tr < 0 ? 0 : tr; }
        else        sr = m0 + lrow;
        aSrc[i] = A + sr * (long)K + scol;
    }
    #pragma unroll
    for (int i = 0; i < 2; ++i) {
        int lrow = wv * 16 + i * 8 + srow;          // 0..127
        int scol = ((schk ^ (lrow & 7)) * 8);
        bSrc[i] = Bt + (long)(n0 + lrow) * K + scol;
    }

    f32x4 acc[4][4] = {};
    const int wm = wv >> 1, wn = wv & 1;     // 4 x 2 wave grid
    const int fr = lane & 15, kg = lane >> 4;

    for (int k0 = 0; k0 < K; k0 += 64) {
        __syncthreads();                     // prev tile fully consumed
        #pragma unroll
        for (int i = 0; i < 4; ++i)
            gload_lds16(aSrc[i] + k0, &As[wv * 32 + i * 8][0]);
        #pragma unroll
        for (int i = 0; i < 2; ++i)
            gload_lds16(bSrc[i] + k0, &Bs[wv * 16 + i * 8][0]);
        __syncthreads();                     // vmcnt(0) drained here

        #pragma unroll
        for (int kk = 0; kk < 2; ++kk) {     // two K=32 halves of BK=64
            bf16x8 af[4], bfr[4];
            #pragma unroll
            for (int i2 = 0; i2 < 4; ++i2) {
                int R = wm * 64 + i2 * 16 + fr;
                af[i2] = *(const bf16x8*)&As[R][((kk * 4 + kg) ^ (R & 7)) * 8];
            }
            #pragma unroll
            for (int j2 = 0; j2 < 4; ++j2) {
                int R = wn * 64 + j2 * 16 + fr;
                bfr[j2] = *(const bf16x8*)&Bs[R][((kk * 4 + kg) ^ (R & 7)) * 8];
            }
            #pragma unroll
            for (int i2 = 0; i2 < 4; ++i2)
                #pragma unroll
                for (int j2 = 0; j2 < 4; ++j2)
                    acc[i2][j2] = __builtin_amdgcn_mfma_f32_16x16x32_bf16(
                        af[i2], bfr[j2], acc[i2][j2], 0, 0, 0);
        }
    }

    // epilogue: C/D layout col = lane&15, row = (lane>>4)*4 + r
    const int colL = lane & 15, rgrp = (lane >> 4) * 4;
    #pragma unroll
    for (int i2 = 0; i2 < 4; ++i2) {
        #pragma unroll
        for (int r = 0; r < 4; ++r) {
            int gm = m0 + wm * 64 + i2 * 16 + rgrp + r;
            int token = gm; float sc = 1.0f;
            if (SCATTER) {
                token = tab[gm];
                if (token < 0) continue;
                sc = rs[token];
            } else if (ROWSCALE) {
                sc = rs[gm];
            }
            #pragma unroll
            for (int j2 = 0; j2 < 4; ++j2) {
                int gn = n0 + wn * 64 + j2 * 16 + colL;
                float v = acc[i2][j2][r] + (bptr ? bptr[gn] : 0.0f);
                if (RELU) v = fmaxf(v, 0.0f);
                if (SCATTER) {
                    long idx = (long)token * N + gn;
                    if (OUTBF16) {
                        // in-place bf16 RMW (unique writer per element;
                        // j rewrites this buffer before k each call)
                        Cb[idx] = f2bf(bf2f(Cb[idx]) + v * sc);
                    } else {
                        Cf[idx] += v * sc;
                    }
                } else {
                    if (ROWSCALE) v *= sc;
                    if (OUTBF16) Cb[(long)gm * N + gn] = f2bf(v);
                    else         Cf[(long)gm * N + gn] = v;
                }
            }
        }
    }
}

// ---------------------------------------------------------------------------
// Transpose + cast: W[K][N] f32 -> Wt[N][K] bf16, 64x64 LDS tiles. z batched.
// ---------------------------------------------------------------------------
__global__ __launch_bounds__(256)
void transpose_cast_k(const float* __restrict__ W, unsigned short* __restrict__ Wt,
                      int K, int N, long wB, long wtB)
{
    const int z = blockIdx.z;
    W  += (long)z * wB;
    Wt += (long)z * wtB;
    __shared__ float tile[64][65];
    const int k0 = blockIdx.x * 64, n0 = blockIdx.y * 64;
    const int c = threadIdx.x & 63, r4 = threadIdx.x >> 6;
    #pragma unroll 4
    for (int it = 0; it < 16; ++it) {
        int row = it * 4 + r4;
        tile[row][c] = W[(long)(k0 + row) * N + n0 + c];
    }
    __syncthreads();
    #pragma unroll 4
    for (int it = 0; it < 16; ++it) {
        int nrow = it * 4 + r4;
        Wt[(long)(n0 + nrow) * K + k0 + c] = f2bf(tile[c][nrow]);
    }
}

// ---------------------------------------------------------------------------
// Wsmall: Wg'[H][8] = W_in @ W_gate, Wc'[H][2] = W_in @ W_coef  (f32)
// ---------------------------------------------------------------------------
__global__ __launch_bounds__(256)
void wsmall_k(const float* __restrict__ W_in, const float* __restrict__ W_gate,
              const float* __restrict__ W_coef,
              float* __restrict__ wgp, float* __restrict__ wcp)
{
    const int r = blockIdx.x * 4 + (threadIdx.x >> 6);
    const int lane = threadIdx.x & 63;
    float s[10] = {};
    for (int k = lane; k < HD; k += 64) {
        float a = W_in[(long)r * HD + k];
        const float4* g = (const float4*)(W_gate + (long)k * 8);
        float4 g0 = g[0], g1 = g[1];
        s[0] += a * g0.x; s[1] += a * g0.y; s[2] += a * g0.z; s[3] += a * g0.w;
        s[4] += a * g1.x; s[5] += a * g1.y; s[6] += a * g1.z; s[7] += a * g1.w;
        float2 cv = *(const float2*)(W_coef + (long)k * 2);
        s[8] += a * cv.x; s[9] += a * cv.y;
    }
    #pragma unroll
    for (int off = 32; off > 0; off >>= 1)
        #pragma unroll
        for (int e = 0; e < 10; ++e) s[e] += __shfl_xor(s[e], off);
    if (lane == 0) {
        #pragma unroll
        for (int e = 0; e < 8; ++e) wgp[(long)r * 8 + e] = s[e];
        wcp[(long)r * 2 + 0] = s[8];
        wcp[(long)r * 2 + 1] = s[9];
    }
}

// bg[8] = b_in @ W_gate ; bc[2] = b_in @ W_coef + b_coef
__global__ void gbias_k(const float* __restrict__ b_in, const float* __restrict__ W_gate,
                        const float* __restrict__ W_coef, const float* __restrict__ b_coef,
                        float* __restrict__ bg, float* __restrict__ bc)
{
    const int lane = threadIdx.x;  // 64
    float s[10] = {};
    for (int k = lane; k < HD; k += 64) {
        float a = b_in[k];
        const float4* g = (const float4*)(W_gate + (long)k * 8);
        float4 g0 = g[0], g1 = g[1];
        s[0] += a * g0.x; s[1] += a * g0.y; s[2] += a * g0.z; s[3] += a * g0.w;
        s[4] += a * g1.x; s[5] += a * g1.y; s[6] += a * g1.z; s[7] += a * g1.w;
        float2 cv = *(const float2*)(W_coef + (long)k * 2);
        s[8] += a * cv.x; s[9] += a * cv.y;
    }
    #pragma unroll
    for (int off = 32; off > 0; off >>= 1)
        #pragma unroll
        for (int e = 0; e < 10; ++e) s[e] += __shfl_xor(s[e], off);
    if (lane == 0) {
        #pragma unroll
        for (int e = 0; e < 8; ++e) bg[e] = s[e];
        bc[0] = s[8] + b_coef[0];
        bc[1] = s[9] + b_coef[1];
    }
}

// ---------------------------------------------------------------------------
// Gating from x with fused weights (one wave per token) + fused x->bf16 cast.
// ---------------------------------------------------------------------------
__global__ __launch_bounds__(256)
void gating_k(const float* __restrict__ x,
              const float* __restrict__ Wg,   // [H,8] fused
              const float* __restrict__ Wc,   // [H,2] fused
              const float* __restrict__ bg,   // [8]
              const float* __restrict__ bc,   // [2]
              unsigned short* __restrict__ xb,
              int* __restrict__ eidx,
              float* __restrict__ gval,
              float* __restrict__ coef0,
              float* __restrict__ coef1)
{
    const int tok = (blockIdx.x * 256 + threadIdx.x) >> 6;
    const int lane = threadIdx.x & 63;
    const float* row = x + (long)tok * HD;
    unsigned short* orow = xb + (long)tok * HD;

    float acc[8] = {};
    float c0 = 0.f, c1 = 0.f;
    for (int i = 0; i < HD / 64; ++i) {
        int k = i * 64 + lane;
        float tv = row[k];
        orow[k] = f2bf(tv);                      // fused x -> bf16 (coalesced)
        const float4* wg = (const float4*)(Wg + (long)k * 8);
        float4 w0 = wg[0], w1 = wg[1];
        acc[0] = fmaf(tv, w0.x, acc[0]); acc[1] = fmaf(tv, w0.y, acc[1]);
        acc[2] = fmaf(tv, w0.z, acc[2]); acc[3] = fmaf(tv, w0.w, acc[3]);
        acc[4] = fmaf(tv, w1.x, acc[4]); acc[5] = fmaf(tv, w1.y, acc[5]);
        acc[6] = fmaf(tv, w1.z, acc[6]); acc[7] = fmaf(tv, w1.w, acc[7]);
        float2 wcv = *(const float2*)(Wc + (long)k * 2);
        c0 = fmaf(tv, wcv.x, c0);
        c1 = fmaf(tv, wcv.y, c1);
    }
    #pragma unroll
    for (int off = 32; off > 0; off >>= 1) {
        #pragma unroll
        for (int e = 0; e < 8; ++e) acc[e] += __shfl_xor(acc[e], off);
        c0 += __shfl_xor(c0, off);
        c1 += __shfl_xor(c1, off);
    }
    if (lane == 0) {
        #pragma unroll
        for (int e = 0; e < 8; ++e) acc[e] += bg[e];
        float m = acc[0]; int best = 0;
        #pragma unroll
        for (int e = 1; e < 8; ++e) if (acc[e] > m) { m = acc[e]; best = e; }
        float s = 0.f;
        #pragma unroll
        for (int e = 0; e < 8; ++e) s += expf(acc[e] - m);
        eidx[tok] = best;
        gval[tok] = 1.0f / s;
        float l0 = c0 + bc[0], l1 = c1 + bc[1];
        float mm = fmaxf(l0, l1);
        float e0 = expf(l0 - mm), e1 = expf(l1 - mm);
        float inv = 1.0f / (e0 + e1);
        coef0[tok] = e0 * inv;
        coef1[tok] = e1 * inv;
    }
}

// ---------------------------------------------------------------------------
// Parallel capacity scan, 3 phases (integer-exact, verified round 5).
// ---------------------------------------------------------------------------
__global__ void scan_hist_k(const int* __restrict__ eidx,
                            int* __restrict__ counts,
                            int* __restrict__ idxTab)
{
    const int b = blockIdx.x;          // chunk id, 0..255
    const int lane = threadIdx.x;      // 64
    for (int j = b * 64 + lane; j < NE * CAP; j += NCHUNK * 64)
        idxTab[j] = -1;
    int e = eidx[b * 64 + lane];
    #pragma unroll
    for (int ex = 0; ex < NE; ++ex) {
        unsigned long long msk = __ballot(e == ex);
        if (lane == ex) counts[b * NE + ex] = (int)__popcll(msk);
    }
}

__global__ void scan_offsets_k(const int* __restrict__ counts,
                               int* __restrict__ offsets)
{
    const int e = threadIdx.x;         // 64 threads, 8 active
    if (e < NE) {
        int run = 0;
        for (int b = 0; b < NCHUNK; ++b) {
            offsets[b * NE + e] = run;
            run += counts[b * NE + e];
        }
    }
}

__global__ void scan_fill_k(const int* __restrict__ eidx,
                            const float* __restrict__ gval,
                            const float* __restrict__ coef0,
                            const int* __restrict__ offsets,
                            int* __restrict__ idxTab,
                            float* __restrict__ smoe)
{
    const int b = blockIdx.x;
    const int lane = threadIdx.x;
    const int tok = b * 64 + lane;
    int e = eidx[tok];
    unsigned long long below = (lane == 0) ? 0ull : ((~0ull) >> (64 - lane));
    int myrank = 0;
    #pragma unroll
    for (int ex = 0; ex < NE; ++ex) {
        unsigned long long msk = __ballot(e == ex);
        if (e == ex) myrank = (int)__popcll(msk & below) + offsets[b * NE + ex];
    }
    if (myrank < CAP) {
        idxTab[e * CAP + myrank] = tok;
        smoe[tok] = gval[tok] * coef0[tok];
    } else {
        smoe[tok] = 0.0f;
    }
}

// ---------------------------------------------------------------------------
// Workspace plan (lifetime-aliased; ~135 MB):
//   slotA [0,32Mi):   W1T (prep) then res1 (i..j)
//   h     [32,72Mi);  t_b [72,104Mi) (f..i) then mixb [72,104Mi) (j..m);
//   W2T [104,120Mi); WinT/Wr1T/Wr2T/WoutT [120..128Mi); small [128Mi..)
//   xb: d_out[0,32Mi) bf16 (gating..f);  out: d_out f32 (written m)
// ---------------------------------------------------------------------------
extern "C" void kernel_launch(void* const* d_in, const int* in_sizes, int n_in,
                              void* d_out, int out_size, void* d_ws, size_t ws_size,
                              hipStream_t stream)
{
    const float* x      = (const float*)d_in[0];
    const float* W_in   = (const float*)d_in[1];
    const float* b_in   = (const float*)d_in[2];
    const float* W_gate = (const float*)d_in[3];
    const float* W1     = (const float*)d_in[4];
    const float* b1     = (const float*)d_in[5];
    const float* W2     = (const float*)d_in[6];
    const float* b2     = (const float*)d_in[7];
    const float* Wr1    = (const float*)d_in[8];
    const float* br1    = (const float*)d_in[9];
    const float* Wr2    = (const float*)d_in[10];
    const float* br2    = (const float*)d_in[11];
    const float* W_coef = (const float*)d_in[12];
    const float* b_coef = (const float*)d_in[13];
    const float* W_out  = (const float*)d_in[14];
    const float* b_out  = (const float*)d_in[15];
    float* out = (float*)d_out;

    const size_t MiB = 1024 * 1024;
    char* ws = (char*)d_ws;
    unsigned short* W1T  = (unsigned short*)(ws + 0);          // 16 MiB (prep)
    unsigned short* res1 = (unsigned short*)(ws + 0);          // 32 MiB (i..j)
    unsigned short* h    = (unsigned short*)(ws + 32 * MiB);   // 40 MiB
    unsigned short* t_b  = (unsigned short*)(ws + 72 * MiB);   // 32 MiB (f..i)
    unsigned short* mixb = (unsigned short*)(ws + 72 * MiB);   // 32 MiB (j..m)
    unsigned short* W2T  = (unsigned short*)(ws + 104 * MiB);  // 16 MiB
    unsigned short* WinT = (unsigned short*)(ws + 120 * MiB);  // 2 MiB
    unsigned short* Wr1T = (unsigned short*)(ws + 122 * MiB);  // 2 MiB
    unsigned short* Wr2T = (unsigned short*)(ws + 124 * MiB);  // 2 MiB
    unsigned short* WoutT= (unsigned short*)(ws + 126 * MiB);  // 2 MiB
    char* sm = ws + 128 * MiB;
    float* wgp  = (float*)(sm);            sm += HD * 8 * 4;
    float* wcp  = (float*)(sm);            sm += HD * 2 * 4;
    float* bg   = (float*)(sm);            sm += 64;
    float* bc   = (float*)(sm);            sm += 64;
    int*   eidx = (int*)(sm);              sm += T_TOK * 4;
    float* gval = (float*)(sm);            sm += T_TOK * 4;
    float* cf0  = (float*)(sm);            sm += T_TOK * 4;
    float* cf1  = (float*)(sm);            sm += T_TOK * 4;
    float* smoe = (float*)(sm);            sm += T_TOK * 4;
    int* idxTab = (int*)(sm);              sm += NE * CAP * 4;
    int* counts = (int*)(sm);              sm += NCHUNK * NE * 4;
    int* offs   = (int*)(sm);              sm += NCHUNK * NE * 4;
    unsigned short* xb = (unsigned short*)d_out;   // 32 MiB, dies after f
    (void)ws_size; (void)in_sizes; (void)n_in; (void)out_size;

    dim3 blk(256);
    dim3 blkG(512);
    dim3 gT(16, 16, 1);
    dim3 gT8(16, 16, 8);
    dim3 gBig(HD / 128, T_TOK / 256, 1);   // 8 x 64 = 512 blocks (%8==0)
    dim3 gExp(HD / 128, CAP / 256, NE);    // 8 x 10 x 8 = 640 blocks (%8==0)

    // b. weight transposes (bf16 [N][K])
    transpose_cast_k<<<gT,  blk, 0, stream>>>(W_in,  WinT,  HD, HD, 0, 0);
    transpose_cast_k<<<gT,  blk, 0, stream>>>(Wr1,   Wr1T,  HD, HD, 0, 0);
    transpose_cast_k<<<gT,  blk, 0, stream>>>(Wr2,   Wr2T,  HD, HD, 0, 0);
    transpose_cast_k<<<gT,  blk, 0, stream>>>(W_out, WoutT, HD, HD, 0, 0);
    transpose_cast_k<<<gT8, blk, 0, stream>>>(W1, W1T, HD, HD, (long)HD * HD, (long)HD * HD);
    transpose_cast_k<<<gT8, blk, 0, stream>>>(W2, W2T, HD, HD, (long)HD * HD, (long)HD * HD);
    // c. fused gating weights (f32)
    wsmall_k<<<HD / 4, blk, 0, stream>>>(W_in, W_gate, W_coef, wgp, wcp);
    gbias_k<<<1, 64, 0, stream>>>(b_in, W_gate, W_coef, b_coef, bg, bc);
    // d. gating from x (f32 routing path) + fused x->bf16 cast
    gating_k<<<T_TOK / 4, blk, 0, stream>>>(x, wgp, wcp, bg, bc, xb,
                                            eidx, gval, cf0, cf1);
    // e. parallel capacity scan
    scan_hist_k<<<NCHUNK, 64, 0, stream>>>(eidx, counts, idxTab);
    scan_offsets_k<<<1, 64, 0, stream>>>(counts, offs);
    scan_fill_k<<<NCHUNK, 64, 0, stream>>>(eidx, gval, cf0, offs, idxTab, smoe);
    // f. t_b = bf16(xb @ W_in + b_in)
    gemm_bf16_k<false, false, false, false, true><<<gBig, blkG, 0, stream>>>(
        xb, WinT, b_in, t_b, T_TOK, HD, HD, nullptr, nullptr,
        0, 0, 0, 0, 0);
    // h. h[e] = relu(gather(t_b) @ W1[e] + b1[e])   bf16 out, empty-tile exit
    gemm_bf16_k<true, true, false, false, true><<<gExp, blkG, 0, stream>>>(
        t_b, W1T, b1, h, CAP, HD, HD, idxTab, nullptr,
        0, (long)HD * HD, HD, CAP, (long)CAP * HD);
    // i. res1 = relu(t_b @ Wr1 + br1)   bf16 out (overlays W1T slot)
    gemm_bf16_k<false, true, false, false, true><<<gBig, blkG, 0, stream>>>(
        t_b, Wr1T, br1, res1, T_TOK, HD, HD, nullptr, nullptr,
        0, 0, 0, 0, 0);
    // j. mixb = bf16((res1 @ Wr2 + br2) * cf1[row])   bf16 -> t_b slot
    //    (t_b dead after h/i; halves j's WRITE vs f32 mix)
    gemm_bf16_k<false, false, true, false, true><<<gBig, blkG, 0, stream>>>(
        res1, Wr2T, br2, mixb, T_TOK, HD, HD, nullptr, cf1,
        0, 0, 0, 0, 0);
    // k. mixb[tok] = bf16(f32(mixb[tok]) + (h[e]@W2[e]+b2[e])*smoe[tok])
    //    in-place bf16 RMW, empty-tile exit; dropped rows already final from j
    gemm_bf16_k<false, false, false, true, true><<<gExp, blkG, 0, stream>>>(
        h, W2T, b2, mixb, CAP, HD, HD, idxTab, smoe,
        (long)CAP * HD, (long)HD * HD, HD, CAP, 0);
    // m. out = mixb @ W_out + b_out   f32 -> d_out
    gemm_bf16_k<false, false, false, false, false><<<gBig, blkG, 0, stream>>>(
        mixb, WoutT, b_out, out, T_TOK, HD, HD, nullptr, nullptr,
        0, 0, 0, 0, 0);
}